// Round 9
// baseline (317.599 us; speedup 1.0000x reference)
//
#include <hip/hip_runtime.h>

#define N_LOC 100000
#define N_EVT 100000
#define N_EDGE 1600000
#define NB 391        // ceil(N_LOC/256) buckets of 256 dst values
#define BCAP 5120     // bucket capacity: avg 4096 + 16 sigma
#define TILE 4096     // edges per k_bin block (256 thr x 16)
#define RB 32         // rows per block in dense kernels
#define RW 8          // rows per wave

__device__ __forceinline__ unsigned bf16_rne(float x) {
    unsigned u = __float_as_uint(x);
    return (u + 0x7fffu + ((u >> 16) & 1u)) >> 16;
}
__device__ __forceinline__ float bf_lo(unsigned u) { return __uint_as_float(u << 16); }
__device__ __forceinline__ float bf_hi(unsigned u) { return __uint_as_float(u & 0xffff0000u); }

#define FMA4(a, wv, acc)                                                        \
    acc = fmaf(a.x, wv.x, acc); acc = fmaf(a.y, wv.y, acc);                     \
    acc = fmaf(a.z, wv.z, acc); acc = fmaf(a.w, wv.w, acc);

// ---------------------------------------------------------------------------
// K1: evt_x = relu(evt_feat @ W_evt + b_evt) -> packed bf16 [N_EVT x 32 uint]
// Block stages 32 rows (16 KB, coalesced memcpy). Wave computes 8 rows x 64
// cols: activations via same-addr LDS broadcast, weights via b128 lane-stride.
// ---------------------------------------------------------------------------
__global__ __launch_bounds__(256) void k_evt(const float* __restrict__ feat,
                                             const float* __restrict__ W,
                                             const float* __restrict__ b,
                                             unsigned* __restrict__ outb) {
    __shared__ float4 sW[32 * 64];   // 32 KB, [j4][c] = W rows 4j4..4j4+3 col c
    __shared__ float  sA[RB * 128];  // 16 KB
    const int t = threadIdx.x;
    for (int idx = t; idx < 32 * 64; idx += 256) {
        int j4 = idx >> 6, c = idx & 63;
        sW[idx] = make_float4(W[(4 * j4 + 0) * 64 + c], W[(4 * j4 + 1) * 64 + c],
                              W[(4 * j4 + 2) * 64 + c], W[(4 * j4 + 3) * 64 + c]);
    }
    const int gbase = blockIdx.x * RB;
    {
        const float4* src = (const float4*)(feat + (size_t)gbase * 128);
        float4* dst = (float4*)sA;
        for (int idx = t; idx < RB * 32; idx += 256) dst[idx] = src[idx];
    }
    __syncthreads();
    const int lane = t & 63;
    const int w = t >> 6;
    const float bias = b[lane];
    float o[RW];
#pragma unroll
    for (int r = 0; r < RW; ++r) o[r] = bias;
#pragma unroll 1
    for (int jo = 0; jo < 32; jo += 4) {
        float4 w0 = sW[(jo + 0) * 64 + lane];
        float4 w1 = sW[(jo + 1) * 64 + lane];
        float4 w2 = sW[(jo + 2) * 64 + lane];
        float4 w3 = sW[(jo + 3) * 64 + lane];
#pragma unroll
        for (int r = 0; r < RW; ++r) {
            const float4* ar = (const float4*)(sA + (w * RW + r) * 128);
            float4 a0 = ar[jo + 0], a1 = ar[jo + 1];
            float4 a2 = ar[jo + 2], a3 = ar[jo + 3];
            FMA4(a0, w0, o[r]) FMA4(a1, w1, o[r])
            FMA4(a2, w2, o[r]) FMA4(a3, w3, o[r])
        }
    }
    const int cc = lane & 31;
#pragma unroll
    for (int r = 0; r < RW; ++r) {
        float oc = fmaxf(o[r], 0.0f);
        float lo = __shfl(oc, 2 * cc);
        float hi = __shfl(oc, 2 * cc + 1);
        unsigned u = bf16_rne(lo) | (bf16_rne(hi) << 16);
        if (lane < 32) outb[(size_t)(gbase + w * RW + r) * 32 + cc] = u;
    }
}

// ---------------------------------------------------------------------------
// K2: loc_x = relu([loc_feat || emb[qid]] @ W_loc + b_loc)  [N_LOC x 64] fp32
// ---------------------------------------------------------------------------
__global__ __launch_bounds__(256) void k_loc(const float* __restrict__ feat,
                                             const int* __restrict__ qid,
                                             const float* __restrict__ emb,
                                             const float* __restrict__ W,
                                             const float* __restrict__ b,
                                             float* __restrict__ out) {
    __shared__ float4 sW[36 * 64];   // 36 KB
    __shared__ float  sA[RB * 128];  // 16 KB
    __shared__ float  sE[RB * 16];   // 2 KB
    const int t = threadIdx.x;
    for (int idx = t; idx < 36 * 64; idx += 256) {
        int j4 = idx >> 6, c = idx & 63;
        sW[idx] = make_float4(W[(4 * j4 + 0) * 64 + c], W[(4 * j4 + 1) * 64 + c],
                              W[(4 * j4 + 2) * 64 + c], W[(4 * j4 + 3) * 64 + c]);
    }
    const int gbase = blockIdx.x * RB;
    {
        const float4* src = (const float4*)(feat + (size_t)gbase * 128);
        float4* dst = (float4*)sA;
        for (int idx = t; idx < RB * 32; idx += 256) dst[idx] = src[idx];
    }
    for (int idx = t; idx < RB * 16; idx += 256) {
        int row = idx >> 4, e = idx & 15;
        sE[idx] = emb[(size_t)qid[gbase + row] * 16 + e];
    }
    __syncthreads();
    const int lane = t & 63;
    const int w = t >> 6;
    const float bias = b[lane];
    float o[RW];
#pragma unroll
    for (int r = 0; r < RW; ++r) o[r] = bias;
#pragma unroll 1
    for (int jo = 0; jo < 32; jo += 4) {
        float4 w0 = sW[(jo + 0) * 64 + lane];
        float4 w1 = sW[(jo + 1) * 64 + lane];
        float4 w2 = sW[(jo + 2) * 64 + lane];
        float4 w3 = sW[(jo + 3) * 64 + lane];
#pragma unroll
        for (int r = 0; r < RW; ++r) {
            const float4* ar = (const float4*)(sA + (w * RW + r) * 128);
            float4 a0 = ar[jo + 0], a1 = ar[jo + 1];
            float4 a2 = ar[jo + 2], a3 = ar[jo + 3];
            FMA4(a0, w0, o[r]) FMA4(a1, w1, o[r])
            FMA4(a2, w2, o[r]) FMA4(a3, w3, o[r])
        }
    }
    {   // embedding tail: dims 128..143 (4 float4 frags)
        float4 w0 = sW[32 * 64 + lane];
        float4 w1 = sW[33 * 64 + lane];
        float4 w2 = sW[34 * 64 + lane];
        float4 w3 = sW[35 * 64 + lane];
#pragma unroll
        for (int r = 0; r < RW; ++r) {
            const float4* er = (const float4*)(sE + (w * RW + r) * 16);
            float4 a0 = er[0], a1 = er[1], a2 = er[2], a3 = er[3];
            FMA4(a0, w0, o[r]) FMA4(a1, w1, o[r])
            FMA4(a2, w2, o[r]) FMA4(a3, w3, o[r])
        }
    }
#pragma unroll
    for (int r = 0; r < RW; ++r)
        out[(size_t)(gbase + w * RW + r) * 64 + lane] = fmaxf(o[r], 0.0f);
}

// ---------------------------------------------------------------------------
// k_bin: bucket edges by dst>>8; payload packed to 4B: src(24b) | dstlow(8b).
// ---------------------------------------------------------------------------
__global__ __launch_bounds__(256) void k_bin(const int* __restrict__ ei,
                                             int* __restrict__ bucket_cnt,
                                             unsigned* __restrict__ binned, int n) {
    __shared__ int h[NB];
    __shared__ int base[NB];
    const int t = threadIdx.x;
    for (int i = t; i < NB; i += 256) h[i] = 0;
    __syncthreads();
    const int e0 = blockIdx.x * TILE;
    int src[16], dst[16], rnk[16];
#pragma unroll
    for (int j = 0; j < 16; ++j) {
        int e = e0 + j * 256 + t;
        if (e < n) {
            src[j] = ei[e];
            dst[j] = ei[n + e];
            rnk[j] = atomicAdd(&h[dst[j] >> 8], 1);
        }
    }
    __syncthreads();
    for (int i = t; i < NB; i += 256) {
        int c = h[i];
        base[i] = (c > 0) ? atomicAdd(&bucket_cnt[i], c) : 0;
    }
    __syncthreads();
#pragma unroll
    for (int j = 0; j < 16; ++j) {
        int e = e0 + j * 256 + t;
        if (e < n) {
            int b = dst[j] >> 8;
            int idx = base[b] + rnk[j];
            if (idx < BCAP)
                binned[(size_t)b * BCAP + idx] =
                    (unsigned)src[j] | ((unsigned)(dst[j] & 255) << 24);
        }
    }
}

// ---------------------------------------------------------------------------
// k_bscan: exclusive scan of the 391 bucket counts (single block).
// ---------------------------------------------------------------------------
__global__ __launch_bounds__(512) void k_bscan(const int* __restrict__ bucket_cnt,
                                               int* __restrict__ csr_off) {
    __shared__ int sd[512];
    const int t = threadIdx.x;
    int v = (t < NB) ? min(bucket_cnt[t], BCAP) : 0;
    sd[t] = v;
    __syncthreads();
    for (int off = 1; off < 512; off <<= 1) {
        int x = (t >= off) ? sd[t - off] : 0;
        __syncthreads();
        sd[t] += x;
        __syncthreads();
    }
    if (t < NB) csr_off[t] = sd[t] - v;
    if (t == NB - 1) csr_off[NB] = sd[t];
}

// ---------------------------------------------------------------------------
// k_bfill: one block per bucket: LDS degree hist -> scan -> deg/row_ex, then
// scatter csr with LDS cursors (writes confined to ~16KB window).
// ---------------------------------------------------------------------------
__global__ __launch_bounds__(256) void k_bfill(const int* __restrict__ bucket_cnt,
                                               const int* __restrict__ csr_off,
                                               const unsigned* __restrict__ binned,
                                               int* __restrict__ deg,
                                               int* __restrict__ row_ex,
                                               int* __restrict__ csr) {
    __shared__ int degl[256];
    __shared__ int sc[256];
    __shared__ int cur[256];
    const int b = blockIdx.x;
    const int t = threadIdx.x;
    const int nb = min(bucket_cnt[b], BCAP);
    const unsigned* bin = binned + (size_t)b * BCAP;
    degl[t] = 0;
    __syncthreads();
    for (int i = t; i < nb; i += 256)
        atomicAdd(&degl[bin[i] >> 24], 1);
    __syncthreads();
    const int v = degl[t];
    sc[t] = v;
    __syncthreads();
    for (int off = 1; off < 256; off <<= 1) {
        int x = (t >= off) ? sc[t - off] : 0;
        __syncthreads();
        sc[t] += x;
        __syncthreads();
    }
    const int ex = csr_off[b] + sc[t] - v;
    const int loc = b * 256 + t;
    if (loc < N_LOC) { deg[loc] = v; row_ex[loc] = ex; }
    cur[t] = ex;
    __syncthreads();
    for (int i = t; i < nb; i += 256) {
        unsigned u = bin[i];
        int pos = atomicAdd(&cur[u >> 24], 1);
        csr[pos] = (int)(u & 0x00FFFFFFu);
    }
}

// ---------------------------------------------------------------------------
// K4: mean[loc] from bf16-packed evt rows. One wave per loc. No LDS, lean
// VGPRs, launch_bounds(256,8) -> full occupancy for the latency-bound gather.
// 2 edges per load instr (32 lanes/row, 2 chans/lane), unroll 8 deep.
// ---------------------------------------------------------------------------
__global__ __launch_bounds__(256, 8) void k_aggr(const unsigned* __restrict__ evtb,
                                                 const int* __restrict__ row_ex,
                                                 const int* __restrict__ deg,
                                                 const int* __restrict__ csr,
                                                 float* __restrict__ meanb, int n) {
    const int lane = threadIdx.x & 63;
    const int wid = (blockIdx.x * 256 + threadIdx.x) >> 6;
    if (wid >= n) return;
    const int beg = row_ex[wid];
    const int cnt = deg[wid];
    const int half = lane >> 5;   // which edge of the pair
    const int c = lane & 31;      // channel-pair index
    float a0 = 0.0f, a1 = 0.0f;
    int i = 0;
    for (; i + 8 <= cnt; i += 8) {
        const int bb = beg + i + half;
        int s0 = csr[bb + 0];
        int s1 = csr[bb + 2];
        int s2 = csr[bb + 4];
        int s3 = csr[bb + 6];
        unsigned u0 = evtb[(size_t)s0 * 32 + c];
        unsigned u1 = evtb[(size_t)s1 * 32 + c];
        unsigned u2 = evtb[(size_t)s2 * 32 + c];
        unsigned u3 = evtb[(size_t)s3 * 32 + c];
        a0 += (bf_lo(u0) + bf_lo(u1)) + (bf_lo(u2) + bf_lo(u3));
        a1 += (bf_hi(u0) + bf_hi(u1)) + (bf_hi(u2) + bf_hi(u3));
    }
    for (; i < cnt; i += 2) {
        int idx = i + half;
        if (idx < cnt) {
            int s = csr[beg + idx];
            unsigned u = evtb[(size_t)s * 32 + c];
            a0 += bf_lo(u);
            a1 += bf_hi(u);
        }
    }
    a0 += __shfl_xor(a0, 32);
    a1 += __shfl_xor(a1, 32);
    const float inv = 1.0f / (float)max(cnt, 1);
    if (lane < 32) {
        float2 mv = make_float2(a0 * inv, a1 * inv);
        *((float2*)(meanb + (size_t)wid * 64 + 2 * c)) = mv;
    }
}

// ---------------------------------------------------------------------------
// K5: x2 = relu(mean @ W_l + b_l + locx @ W_r); h = relu(x2 @ W_h1 + b_h1);
//     out = h @ W_h2 + b_h2.  Block-staged like k_loc; x2 aliased onto sM.
// ---------------------------------------------------------------------------
__global__ __launch_bounds__(256) void k_comb(
    const float* __restrict__ meanb, const float* __restrict__ locx,
    const float* __restrict__ W_l, const float* __restrict__ b_l,
    const float* __restrict__ W_r,
    const float* __restrict__ W_h1, const float* __restrict__ b_h1,
    const float* __restrict__ W_h2, const float* __restrict__ b_h2,
    float* __restrict__ out)
{
    __shared__ float4 sWl[16 * 64];   // 16 KB
    __shared__ float4 sWr[16 * 64];   // 16 KB
    __shared__ float4 sWh1[16 * 32];  // 8 KB
    __shared__ float  sWh2[32];
    __shared__ float  sM[RB * 64];    // 8 KB (reused as x2 after layer 1)
    __shared__ float  sX[RB * 64];    // 8 KB
    const int t = threadIdx.x;
    for (int idx = t; idx < 16 * 64; idx += 256) {
        int j4 = idx >> 6, c = idx & 63;
        sWl[idx] = make_float4(W_l[(4 * j4 + 0) * 64 + c], W_l[(4 * j4 + 1) * 64 + c],
                               W_l[(4 * j4 + 2) * 64 + c], W_l[(4 * j4 + 3) * 64 + c]);
        sWr[idx] = make_float4(W_r[(4 * j4 + 0) * 64 + c], W_r[(4 * j4 + 1) * 64 + c],
                               W_r[(4 * j4 + 2) * 64 + c], W_r[(4 * j4 + 3) * 64 + c]);
    }
    for (int idx = t; idx < 16 * 32; idx += 256) {
        int j4 = idx >> 5, k = idx & 31;
        sWh1[idx] = make_float4(W_h1[(4 * j4 + 0) * 32 + k], W_h1[(4 * j4 + 1) * 32 + k],
                                W_h1[(4 * j4 + 2) * 32 + k], W_h1[(4 * j4 + 3) * 32 + k]);
    }
    if (t < 32) sWh2[t] = W_h2[t];
    const int gbase = blockIdx.x * RB;
    {
        const float4* srcm = (const float4*)(meanb + (size_t)gbase * 64);
        const float4* srcx = (const float4*)(locx + (size_t)gbase * 64);
        float4* dm = (float4*)sM;
        float4* dx = (float4*)sX;
        for (int idx = t; idx < RB * 16; idx += 256) { dm[idx] = srcm[idx]; dx[idx] = srcx[idx]; }
    }
    __syncthreads();
    const int lane = t & 63;
    const int w = t >> 6;
    const int kk = lane & 31;
    const float bl = b_l[lane];
    const float bh1 = b_h1[kk];
    const float bh2 = b_h2[0];
    float o[RW];
#pragma unroll
    for (int r = 0; r < RW; ++r) o[r] = bl;
#pragma unroll 1
    for (int jo = 0; jo < 16; jo += 2) {
        float4 wl0 = sWl[(jo + 0) * 64 + lane];
        float4 wl1 = sWl[(jo + 1) * 64 + lane];
        float4 wr0 = sWr[(jo + 0) * 64 + lane];
        float4 wr1 = sWr[(jo + 1) * 64 + lane];
#pragma unroll
        for (int r = 0; r < RW; ++r) {
            const float4* mr = (const float4*)(sM + (w * RW + r) * 64);
            const float4* xr = (const float4*)(sX + (w * RW + r) * 64);
            float4 ma = mr[jo + 0], mb = mr[jo + 1];
            float4 xa = xr[jo + 0], xb = xr[jo + 1];
            FMA4(ma, wl0, o[r]) FMA4(xa, wr0, o[r])
            FMA4(mb, wl1, o[r]) FMA4(xb, wr1, o[r])
        }
    }
    // x2 -> sM rows (this wave's rows only; same-wave in-order, no barrier)
#pragma unroll
    for (int r = 0; r < RW; ++r)
        sM[(w * RW + r) * 64 + lane] = fmaxf(o[r], 0.0f);
    float h[RW];
#pragma unroll
    for (int r = 0; r < RW; ++r) h[r] = bh1;
#pragma unroll 1
    for (int j4 = 0; j4 < 16; ++j4) {
        float4 wh = sWh1[j4 * 32 + kk];
#pragma unroll
        for (int r = 0; r < RW; ++r) {
            float4 a = ((const float4*)(sM + (w * RW + r) * 64))[j4];
            FMA4(a, wh, h[r])
        }
    }
    const float w2v = sWh2[kk];
#pragma unroll
    for (int r = 0; r < RW; ++r) {
        float v = fmaxf(h[r], 0.0f) * w2v;
#pragma unroll
        for (int m = 16; m >= 1; m >>= 1) v += __shfl_xor(v, m);
        if (lane == 0) out[gbase + w * RW + r] = v + bh2;
    }
}

// ---------------------------------------------------------------------------
extern "C" void kernel_launch(void* const* d_in, const int* in_sizes, int n_in,
                              void* d_out, int out_size, void* d_ws, size_t ws_size,
                              hipStream_t stream) {
    const float* loc_feat = (const float*)d_in[0];
    const float* evt_feat = (const float*)d_in[1];
    const int*   qid      = (const int*)d_in[2];
    const int*   ei       = (const int*)d_in[3];
    const float* emb      = (const float*)d_in[4];
    const float* W_loc    = (const float*)d_in[5];
    const float* b_loc    = (const float*)d_in[6];
    const float* W_evt    = (const float*)d_in[7];
    const float* b_evt    = (const float*)d_in[8];
    const float* W_l      = (const float*)d_in[9];
    const float* b_l      = (const float*)d_in[10];
    const float* W_r      = (const float*)d_in[11];
    const float* W_h1     = (const float*)d_in[12];
    const float* b_h1     = (const float*)d_in[13];
    const float* W_h2     = (const float*)d_in[14];
    const float* b_h2     = (const float*)d_in[15];
    float* out = (float*)d_out;

    char* ws = (char*)d_ws;
    size_t off = 0;
    auto alloc = [&](size_t bytes) -> void* {
        void* p = ws + off;
        off += (bytes + 255) & ~(size_t)255;
        return p;
    };
    unsigned* evtb  = (unsigned*)alloc((size_t)N_EVT * 32 * 4);      // bf16 evt_x (12.8 MB)
    float* loc_x    = (float*)alloc((size_t)N_LOC * 64 * 4);         // 25.6 MB
    float* meanb    = (float*)alloc((size_t)N_LOC * 64 * 4);         // 25.6 MB
    unsigned* binned= (unsigned*)alloc((size_t)NB * BCAP * 4);       // 8 MB packed
    int*   deg      = (int*)alloc((size_t)N_LOC * 4);
    int*   row_ex   = (int*)alloc((size_t)(N_LOC + 1) * 4);
    int*   csr      = (int*)alloc((size_t)N_EDGE * 4);
    int*   bucket_cnt = (int*)alloc((size_t)NB * 4);
    int*   csr_off  = (int*)alloc((size_t)(NB + 1) * 4);
    (void)ws_size; (void)in_sizes; (void)n_in; (void)out_size;

    hipMemsetAsync(bucket_cnt, 0, (size_t)NB * 4, stream);

    // 100000 = 3125 blocks x 32 rows exactly
    k_evt<<<3125, 256, 0, stream>>>(evt_feat, W_evt, b_evt, evtb);
    k_loc<<<3125, 256, 0, stream>>>(loc_feat, qid, emb, W_loc, b_loc, loc_x);
    k_bin<<<(N_EDGE + TILE - 1) / TILE, 256, 0, stream>>>(ei, bucket_cnt, binned, N_EDGE);
    k_bscan<<<1, 512, 0, stream>>>(bucket_cnt, csr_off);
    k_bfill<<<NB, 256, 0, stream>>>(bucket_cnt, csr_off, binned, deg, row_ex, csr);
    k_aggr<<<N_LOC / 4, 256, 0, stream>>>(evtb, row_ex, deg, csr, meanb, N_LOC);
    k_comb<<<3125, 256, 0, stream>>>(meanb, loc_x, W_l, b_l, W_r, W_h1, b_h1, W_h2, b_h2, out);
}

// Round 10
// 213.411 us; speedup vs baseline: 1.4882x; 1.4882x over previous
//
#include <hip/hip_runtime.h>

#define N_LOC 100000
#define N_EVT 100000
#define N_EDGE 1600000
#define NB 391        // ceil(N_LOC/256) buckets of 256 dst values
#define BCAP 5120     // bucket capacity: avg 4096 + 16 sigma
#define TILE 4096     // edges per k_bin block (256 thr x 16)
#define RBLK 64       // rows per block in dense kernels (4 waves x 16)

__device__ __forceinline__ unsigned bf16_rne(float x) {
    unsigned u = __float_as_uint(x);
    return (u + 0x7fffu + ((u >> 16) & 1u)) >> 16;
}
__device__ __forceinline__ float bf_lo(unsigned u) { return __uint_as_float(u << 16); }
__device__ __forceinline__ float bf_hi(unsigned u) { return __uint_as_float(u & 0xffff0000u); }

// acc(cols 4cg..4cg+3) += av.{x,y,z,w} * W[4k4+{0,1,2,3}][cols]
#define DOT4(av, w0, w1, w2, w3, acc)                                           \
    acc.x = fmaf(av.x, w0.x, acc.x); acc.y = fmaf(av.x, w0.y, acc.y);           \
    acc.z = fmaf(av.x, w0.z, acc.z); acc.w = fmaf(av.x, w0.w, acc.w);           \
    acc.x = fmaf(av.y, w1.x, acc.x); acc.y = fmaf(av.y, w1.y, acc.y);           \
    acc.z = fmaf(av.y, w1.z, acc.z); acc.w = fmaf(av.y, w1.w, acc.w);           \
    acc.x = fmaf(av.z, w2.x, acc.x); acc.y = fmaf(av.z, w2.y, acc.y);           \
    acc.z = fmaf(av.z, w2.z, acc.z); acc.w = fmaf(av.z, w2.w, acc.w);           \
    acc.x = fmaf(av.w, w3.x, acc.x); acc.y = fmaf(av.w, w3.y, acc.y);           \
    acc.z = fmaf(av.w, w3.z, acc.z); acc.w = fmaf(av.w, w3.w, acc.w);

// ---------------------------------------------------------------------------
// K1: evt_x = relu(evt_feat @ W_evt + b_evt) -> packed bf16 [N_EVT x 32 uint]
// 2D tile: lane = (cg: 16 col-groups x 4 cols, rg: 4 row-groups x 4 rows).
// Per k4: 4 weight b128 (16-lane broadcast) + 4 act b128 (16-lane broadcast).
// ---------------------------------------------------------------------------
__global__ __launch_bounds__(256) void k_evt(const float* __restrict__ feat,
                                             const float* __restrict__ W,
                                             const float* __restrict__ b,
                                             unsigned* __restrict__ outb, int n) {
    __shared__ float sW[128 * 64];    // 32 KB, natural row-major copy
    __shared__ float sA[RBLK * 136];  // 34.8 KB, padded stride kills bank alias
    float4* sW4 = (float4*)sW;
    float4* sA4 = (float4*)sA;
    const int t = threadIdx.x;
    const int gbase = blockIdx.x * RBLK;
    for (int idx = t; idx < 2048; idx += 256) sW4[idx] = ((const float4*)W)[idx];
    for (int idx = t; idx < RBLK * 32; idx += 256) {
        int row = idx >> 5, c4 = idx & 31;
        int grow = gbase + row;
        sA4[row * 34 + c4] = (grow < n) ? ((const float4*)feat)[(size_t)grow * 32 + c4]
                                        : make_float4(0.f, 0.f, 0.f, 0.f);
    }
    __syncthreads();
    const int lane = t & 63;
    const int w = t >> 6;
    const int cg = lane & 15;
    const int rg = lane >> 4;
    const int rbase = w * 16 + rg * 4;
    const float4 bias = ((const float4*)b)[cg];
    float4 a0 = bias, a1 = bias, a2 = bias, a3 = bias;
#pragma unroll 2
    for (int k4 = 0; k4 < 32; ++k4) {
        float4 w0 = sW4[(4 * k4 + 0) * 16 + cg];
        float4 w1 = sW4[(4 * k4 + 1) * 16 + cg];
        float4 w2 = sW4[(4 * k4 + 2) * 16 + cg];
        float4 w3 = sW4[(4 * k4 + 3) * 16 + cg];
        float4 v0 = sA4[(rbase + 0) * 34 + k4];
        float4 v1 = sA4[(rbase + 1) * 34 + k4];
        float4 v2 = sA4[(rbase + 2) * 34 + k4];
        float4 v3 = sA4[(rbase + 3) * 34 + k4];
        DOT4(v0, w0, w1, w2, w3, a0)
        DOT4(v1, w0, w1, w2, w3, a1)
        DOT4(v2, w0, w1, w2, w3, a2)
        DOT4(v3, w0, w1, w2, w3, a3)
    }
#define EVT_ST(j, acc)                                                          \
    {                                                                           \
        int grow = gbase + rbase + j;                                           \
        if (grow < n) {                                                         \
            float x = fmaxf(acc.x, 0.f), y = fmaxf(acc.y, 0.f);                 \
            float z = fmaxf(acc.z, 0.f), q = fmaxf(acc.w, 0.f);                 \
            uint2 u = make_uint2(bf16_rne(x) | (bf16_rne(y) << 16),             \
                                 bf16_rne(z) | (bf16_rne(q) << 16));            \
            ((uint2*)outb)[(size_t)grow * 16 + cg] = u;                         \
        }                                                                       \
    }
    EVT_ST(0, a0) EVT_ST(1, a1) EVT_ST(2, a2) EVT_ST(3, a3)
#undef EVT_ST
}

// ---------------------------------------------------------------------------
// K2: loc_x = relu([loc_feat || emb[qid]] @ W_loc + b_loc)  [N_LOC x 64] fp32
// ---------------------------------------------------------------------------
__global__ __launch_bounds__(256) void k_loc(const float* __restrict__ feat,
                                             const int* __restrict__ qid,
                                             const float* __restrict__ emb,
                                             const float* __restrict__ W,
                                             const float* __restrict__ b,
                                             float* __restrict__ out, int n) {
    __shared__ float sW[144 * 64];    // 36 KB
    __shared__ float sA[RBLK * 136];  // 34.8 KB
    __shared__ float sE[RBLK * 20];   // 5.1 KB (16 used, pad to 20)
    float4* sW4 = (float4*)sW;
    float4* sA4 = (float4*)sA;
    float4* sE4 = (float4*)sE;
    const int t = threadIdx.x;
    const int gbase = blockIdx.x * RBLK;
    for (int idx = t; idx < 2304; idx += 256) sW4[idx] = ((const float4*)W)[idx];
    for (int idx = t; idx < RBLK * 32; idx += 256) {
        int row = idx >> 5, c4 = idx & 31;
        int grow = gbase + row;
        sA4[row * 34 + c4] = (grow < n) ? ((const float4*)feat)[(size_t)grow * 32 + c4]
                                        : make_float4(0.f, 0.f, 0.f, 0.f);
    }
    for (int idx = t; idx < RBLK * 4; idx += 256) {
        int row = idx >> 2, e4 = idx & 3;
        int grow = gbase + row;
        int q = (grow < n) ? qid[grow] : 0;
        sE4[row * 5 + e4] = ((const float4*)emb)[(size_t)q * 4 + e4];
    }
    __syncthreads();
    const int lane = t & 63;
    const int w = t >> 6;
    const int cg = lane & 15;
    const int rg = lane >> 4;
    const int rbase = w * 16 + rg * 4;
    const float4 bias = ((const float4*)b)[cg];
    float4 a0 = bias, a1 = bias, a2 = bias, a3 = bias;
#pragma unroll 2
    for (int k4 = 0; k4 < 32; ++k4) {
        float4 w0 = sW4[(4 * k4 + 0) * 16 + cg];
        float4 w1 = sW4[(4 * k4 + 1) * 16 + cg];
        float4 w2 = sW4[(4 * k4 + 2) * 16 + cg];
        float4 w3 = sW4[(4 * k4 + 3) * 16 + cg];
        float4 v0 = sA4[(rbase + 0) * 34 + k4];
        float4 v1 = sA4[(rbase + 1) * 34 + k4];
        float4 v2 = sA4[(rbase + 2) * 34 + k4];
        float4 v3 = sA4[(rbase + 3) * 34 + k4];
        DOT4(v0, w0, w1, w2, w3, a0)
        DOT4(v1, w0, w1, w2, w3, a1)
        DOT4(v2, w0, w1, w2, w3, a2)
        DOT4(v3, w0, w1, w2, w3, a3)
    }
#pragma unroll
    for (int k4 = 0; k4 < 4; ++k4) {  // embedding tail, k = 128..143
        float4 w0 = sW4[(128 + 4 * k4 + 0) * 16 + cg];
        float4 w1 = sW4[(128 + 4 * k4 + 1) * 16 + cg];
        float4 w2 = sW4[(128 + 4 * k4 + 2) * 16 + cg];
        float4 w3 = sW4[(128 + 4 * k4 + 3) * 16 + cg];
        float4 v0 = sE4[(rbase + 0) * 5 + k4];
        float4 v1 = sE4[(rbase + 1) * 5 + k4];
        float4 v2 = sE4[(rbase + 2) * 5 + k4];
        float4 v3 = sE4[(rbase + 3) * 5 + k4];
        DOT4(v0, w0, w1, w2, w3, a0)
        DOT4(v1, w0, w1, w2, w3, a1)
        DOT4(v2, w0, w1, w2, w3, a2)
        DOT4(v3, w0, w1, w2, w3, a3)
    }
#define LOC_ST(j, acc)                                                          \
    {                                                                           \
        int grow = gbase + rbase + j;                                           \
        if (grow < n) {                                                         \
            float4 r = make_float4(fmaxf(acc.x, 0.f), fmaxf(acc.y, 0.f),        \
                                   fmaxf(acc.z, 0.f), fmaxf(acc.w, 0.f));       \
            ((float4*)out)[(size_t)grow * 16 + cg] = r;                         \
        }                                                                       \
    }
    LOC_ST(0, a0) LOC_ST(1, a1) LOC_ST(2, a2) LOC_ST(3, a3)
#undef LOC_ST
}

// ---------------------------------------------------------------------------
// k_bin: bucket edges by dst>>8; payload packed to 4B: src(24b) | dstlow(8b).
// ---------------------------------------------------------------------------
__global__ __launch_bounds__(256) void k_bin(const int* __restrict__ ei,
                                             int* __restrict__ bucket_cnt,
                                             unsigned* __restrict__ binned, int n) {
    __shared__ int h[NB];
    __shared__ int base[NB];
    const int t = threadIdx.x;
    for (int i = t; i < NB; i += 256) h[i] = 0;
    __syncthreads();
    const int e0 = blockIdx.x * TILE;
    int src[16], dst[16], rnk[16];
#pragma unroll
    for (int j = 0; j < 16; ++j) {
        int e = e0 + j * 256 + t;
        if (e < n) {
            src[j] = ei[e];
            dst[j] = ei[n + e];
            rnk[j] = atomicAdd(&h[dst[j] >> 8], 1);
        }
    }
    __syncthreads();
    for (int i = t; i < NB; i += 256) {
        int c = h[i];
        base[i] = (c > 0) ? atomicAdd(&bucket_cnt[i], c) : 0;
    }
    __syncthreads();
#pragma unroll
    for (int j = 0; j < 16; ++j) {
        int e = e0 + j * 256 + t;
        if (e < n) {
            int bk = dst[j] >> 8;
            int idx = base[bk] + rnk[j];
            if (idx < BCAP)
                binned[(size_t)bk * BCAP + idx] =
                    (unsigned)src[j] | ((unsigned)(dst[j] & 255) << 24);
        }
    }
}

// ---------------------------------------------------------------------------
// k_bscan: exclusive scan of the 391 bucket counts (single block).
// ---------------------------------------------------------------------------
__global__ __launch_bounds__(512) void k_bscan(const int* __restrict__ bucket_cnt,
                                               int* __restrict__ csr_off) {
    __shared__ int sd[512];
    const int t = threadIdx.x;
    int v = (t < NB) ? min(bucket_cnt[t], BCAP) : 0;
    sd[t] = v;
    __syncthreads();
    for (int off = 1; off < 512; off <<= 1) {
        int x = (t >= off) ? sd[t - off] : 0;
        __syncthreads();
        sd[t] += x;
        __syncthreads();
    }
    if (t < NB) csr_off[t] = sd[t] - v;
    if (t == NB - 1) csr_off[NB] = sd[t];
}

// ---------------------------------------------------------------------------
// k_bfill: one block per bucket: LDS degree hist -> scan -> deg/row_ex, then
// scatter csr with LDS cursors (writes confined to ~16KB window).
// ---------------------------------------------------------------------------
__global__ __launch_bounds__(256) void k_bfill(const int* __restrict__ bucket_cnt,
                                               const int* __restrict__ csr_off,
                                               const unsigned* __restrict__ binned,
                                               int* __restrict__ deg,
                                               int* __restrict__ row_ex,
                                               int* __restrict__ csr) {
    __shared__ int degl[256];
    __shared__ int sc[256];
    __shared__ int cur[256];
    const int b = blockIdx.x;
    const int t = threadIdx.x;
    const int nb = min(bucket_cnt[b], BCAP);
    const unsigned* bin = binned + (size_t)b * BCAP;
    degl[t] = 0;
    __syncthreads();
    for (int i = t; i < nb; i += 256)
        atomicAdd(&degl[bin[i] >> 24], 1);
    __syncthreads();
    const int v = degl[t];
    sc[t] = v;
    __syncthreads();
    for (int off = 1; off < 256; off <<= 1) {
        int x = (t >= off) ? sc[t - off] : 0;
        __syncthreads();
        sc[t] += x;
        __syncthreads();
    }
    const int ex = csr_off[b] + sc[t] - v;
    const int loc = b * 256 + t;
    if (loc < N_LOC) { deg[loc] = v; row_ex[loc] = ex; }
    cur[t] = ex;
    __syncthreads();
    for (int i = t; i < nb; i += 256) {
        unsigned u = bin[i];
        int pos = atomicAdd(&cur[u >> 24], 1);
        csr[pos] = (int)(u & 0x00FFFFFFu);
    }
}

// ---------------------------------------------------------------------------
// K4: mean[loc] from bf16-packed evt rows. One wave per loc. No LDS, lean
// VGPRs, launch_bounds(256,8) -> full occupancy for the latency-bound gather.
// ---------------------------------------------------------------------------
__global__ __launch_bounds__(256, 8) void k_aggr(const unsigned* __restrict__ evtb,
                                                 const int* __restrict__ row_ex,
                                                 const int* __restrict__ deg,
                                                 const int* __restrict__ csr,
                                                 float* __restrict__ meanb, int n) {
    const int lane = threadIdx.x & 63;
    const int wid = (blockIdx.x * 256 + threadIdx.x) >> 6;
    if (wid >= n) return;
    const int beg = row_ex[wid];
    const int cnt = deg[wid];
    const int half = lane >> 5;
    const int c = lane & 31;
    float a0 = 0.0f, a1 = 0.0f;
    int i = 0;
    for (; i + 8 <= cnt; i += 8) {
        const int bb = beg + i + half;
        int s0 = csr[bb + 0];
        int s1 = csr[bb + 2];
        int s2 = csr[bb + 4];
        int s3 = csr[bb + 6];
        unsigned u0 = evtb[(size_t)s0 * 32 + c];
        unsigned u1 = evtb[(size_t)s1 * 32 + c];
        unsigned u2 = evtb[(size_t)s2 * 32 + c];
        unsigned u3 = evtb[(size_t)s3 * 32 + c];
        a0 += (bf_lo(u0) + bf_lo(u1)) + (bf_lo(u2) + bf_lo(u3));
        a1 += (bf_hi(u0) + bf_hi(u1)) + (bf_hi(u2) + bf_hi(u3));
    }
    for (; i < cnt; i += 2) {
        int idx = i + half;
        if (idx < cnt) {
            int s = csr[beg + idx];
            unsigned u = evtb[(size_t)s * 32 + c];
            a0 += bf_lo(u);
            a1 += bf_hi(u);
        }
    }
    a0 += __shfl_xor(a0, 32);
    a1 += __shfl_xor(a1, 32);
    const float inv = 1.0f / (float)max(cnt, 1);
    if (lane < 32) {
        float2 mv = make_float2(a0 * inv, a1 * inv);
        *((float2*)(meanb + (size_t)wid * 64 + 2 * c)) = mv;
    }
}

// ---------------------------------------------------------------------------
// K5: x2 = relu([mean||locx] @ [W_l;W_r] + b_l); h = relu(x2 @ W_h1 + b_h1);
//     out = h @ W_h2 + b_h2.  Layer 1 = same 2D tile as k_evt on concat K=128.
//     x2 aliases onto wave-private sAB rows.  LDS 74.8 KB -> 2 blocks/CU.
// ---------------------------------------------------------------------------
__global__ __launch_bounds__(256) void k_comb(
    const float* __restrict__ meanb, const float* __restrict__ locx,
    const float* __restrict__ W_l, const float* __restrict__ b_l,
    const float* __restrict__ W_r,
    const float* __restrict__ W_h1, const float* __restrict__ b_h1,
    const float* __restrict__ W_h2, const float* __restrict__ b_h2,
    float* __restrict__ out, int n)
{
    __shared__ float sWc[128 * 64];   // 32 KB: rows 0..63 = W_l, 64..127 = W_r
    __shared__ float sAB[RBLK * 136]; // 34.8 KB: cols 0..63 mean, 64..127 locx
    __shared__ float sWh1[64 * 32];   // 8 KB
    float4* sWc4 = (float4*)sWc;
    float4* sAB4 = (float4*)sAB;
    float4* sWh14 = (float4*)sWh1;
    const int t = threadIdx.x;
    const int gbase = blockIdx.x * RBLK;
    for (int idx = t; idx < 2048; idx += 256)
        sWc4[idx] = (idx < 1024) ? ((const float4*)W_l)[idx] : ((const float4*)W_r)[idx - 1024];
    for (int idx = t; idx < 512; idx += 256) sWh14[idx] = ((const float4*)W_h1)[idx];
    for (int idx = t; idx < RBLK * 16; idx += 256) {
        int row = idx >> 4, c4 = idx & 15;
        int grow = gbase + row;
        float4 mz = make_float4(0.f, 0.f, 0.f, 0.f);
        sAB4[row * 34 + c4]      = (grow < n) ? ((const float4*)meanb)[(size_t)grow * 16 + c4] : mz;
        sAB4[row * 34 + 16 + c4] = (grow < n) ? ((const float4*)locx)[(size_t)grow * 16 + c4] : mz;
    }
    __syncthreads();
    const int lane = t & 63;
    const int w = t >> 6;
    // ---- layer 1 ----
    {
        const int cg = lane & 15;
        const int rg = lane >> 4;
        const int rbase = w * 16 + rg * 4;
        const float4 bias = ((const float4*)b_l)[cg];
        float4 a0 = bias, a1 = bias, a2 = bias, a3 = bias;
#pragma unroll 2
        for (int k4 = 0; k4 < 32; ++k4) {
            float4 w0 = sWc4[(4 * k4 + 0) * 16 + cg];
            float4 w1 = sWc4[(4 * k4 + 1) * 16 + cg];
            float4 w2 = sWc4[(4 * k4 + 2) * 16 + cg];
            float4 w3 = sWc4[(4 * k4 + 3) * 16 + cg];
            float4 v0 = sAB4[(rbase + 0) * 34 + k4];
            float4 v1 = sAB4[(rbase + 1) * 34 + k4];
            float4 v2 = sAB4[(rbase + 2) * 34 + k4];
            float4 v3 = sAB4[(rbase + 3) * 34 + k4];
            DOT4(v0, w0, w1, w2, w3, a0)
            DOT4(v1, w0, w1, w2, w3, a1)
            DOT4(v2, w0, w1, w2, w3, a2)
            DOT4(v3, w0, w1, w2, w3, a3)
        }
        // x2 -> alias onto this wave's own sAB rows (cols 0..15 f4). Same-wave
        // LDS RAW is ordered by the compiler's lgkmcnt; other waves never
        // touch these rows after the initial barrier.
        a0.x = fmaxf(a0.x, 0.f); a0.y = fmaxf(a0.y, 0.f); a0.z = fmaxf(a0.z, 0.f); a0.w = fmaxf(a0.w, 0.f);
        a1.x = fmaxf(a1.x, 0.f); a1.y = fmaxf(a1.y, 0.f); a1.z = fmaxf(a1.z, 0.f); a1.w = fmaxf(a1.w, 0.f);
        a2.x = fmaxf(a2.x, 0.f); a2.y = fmaxf(a2.y, 0.f); a2.z = fmaxf(a2.z, 0.f); a2.w = fmaxf(a2.w, 0.f);
        a3.x = fmaxf(a3.x, 0.f); a3.y = fmaxf(a3.y, 0.f); a3.z = fmaxf(a3.z, 0.f); a3.w = fmaxf(a3.w, 0.f);
        sAB4[(rbase + 0) * 34 + cg] = a0;
        sAB4[(rbase + 1) * 34 + cg] = a1;
        sAB4[(rbase + 2) * 34 + cg] = a2;
        sAB4[(rbase + 3) * 34 + cg] = a3;
    }
    // ---- layer 2 + head ----
    {
        const int cg2 = lane & 7;   // 8 groups x 4 cols = 32 cols
        const int rg2 = lane >> 3;  // 8 groups x 2 rows = 16 rows
        const int rbase = w * 16 + rg2 * 2;
        const float4 bias = ((const float4*)b_h1)[cg2];
        const float4 wh2 = ((const float4*)W_h2)[cg2];
        const float bh2 = b_h2[0];
        float4 h0 = bias, h1 = bias;
#pragma unroll 2
        for (int k4 = 0; k4 < 16; ++k4) {
            float4 w0 = sWh14[(4 * k4 + 0) * 8 + cg2];
            float4 w1 = sWh14[(4 * k4 + 1) * 8 + cg2];
            float4 w2 = sWh14[(4 * k4 + 2) * 8 + cg2];
            float4 w3 = sWh14[(4 * k4 + 3) * 8 + cg2];
            float4 v0 = sAB4[(rbase + 0) * 34 + k4];
            float4 v1 = sAB4[(rbase + 1) * 34 + k4];
            DOT4(v0, w0, w1, w2, w3, h0)
            DOT4(v1, w0, w1, w2, w3, h1)
        }
#pragma unroll
        for (int j = 0; j < 2; ++j) {
            float4 hh = (j == 0) ? h0 : h1;
            float p = fmaxf(hh.x, 0.f) * wh2.x + fmaxf(hh.y, 0.f) * wh2.y +
                      fmaxf(hh.z, 0.f) * wh2.z + fmaxf(hh.w, 0.f) * wh2.w;
            p += __shfl_xor(p, 1);
            p += __shfl_xor(p, 2);
            p += __shfl_xor(p, 4);
            int grow = gbase + rbase + j;
            if (cg2 == 0 && grow < n) out[grow] = p + bh2;
        }
    }
}

// ---------------------------------------------------------------------------
extern "C" void kernel_launch(void* const* d_in, const int* in_sizes, int n_in,
                              void* d_out, int out_size, void* d_ws, size_t ws_size,
                              hipStream_t stream) {
    const float* loc_feat = (const float*)d_in[0];
    const float* evt_feat = (const float*)d_in[1];
    const int*   qid      = (const int*)d_in[2];
    const int*   ei       = (const int*)d_in[3];
    const float* emb      = (const float*)d_in[4];
    const float* W_loc    = (const float*)d_in[5];
    const float* b_loc    = (const float*)d_in[6];
    const float* W_evt    = (const float*)d_in[7];
    const float* b_evt    = (const float*)d_in[8];
    const float* W_l      = (const float*)d_in[9];
    const float* b_l      = (const float*)d_in[10];
    const float* W_r      = (const float*)d_in[11];
    const float* W_h1     = (const float*)d_in[12];
    const float* b_h1     = (const float*)d_in[13];
    const float* W_h2     = (const float*)d_in[14];
    const float* b_h2     = (const float*)d_in[15];
    float* out = (float*)d_out;

    char* ws = (char*)d_ws;
    size_t off = 0;
    auto alloc = [&](size_t bytes) -> void* {
        void* p = ws + off;
        off += (bytes + 255) & ~(size_t)255;
        return p;
    };
    unsigned* evtb  = (unsigned*)alloc((size_t)N_EVT * 32 * 4);      // bf16 evt_x (12.8 MB)
    float* loc_x    = (float*)alloc((size_t)N_LOC * 64 * 4);         // 25.6 MB
    float* meanb    = (float*)alloc((size_t)N_LOC * 64 * 4);         // 25.6 MB
    unsigned* binned= (unsigned*)alloc((size_t)NB * BCAP * 4);       // 8 MB packed
    int*   deg      = (int*)alloc((size_t)N_LOC * 4);
    int*   row_ex   = (int*)alloc((size_t)(N_LOC + 1) * 4);
    int*   csr      = (int*)alloc((size_t)N_EDGE * 4);
    int*   bucket_cnt = (int*)alloc((size_t)NB * 4);
    int*   csr_off  = (int*)alloc((size_t)(NB + 1) * 4);
    (void)ws_size; (void)in_sizes; (void)n_in; (void)out_size;

    hipMemsetAsync(bucket_cnt, 0, (size_t)NB * 4, stream);

    const int dense_grid = (N_LOC + RBLK - 1) / RBLK;  // 1563
    k_evt<<<dense_grid, 256, 0, stream>>>(evt_feat, W_evt, b_evt, evtb, N_EVT);
    k_loc<<<dense_grid, 256, 0, stream>>>(loc_feat, qid, emb, W_loc, b_loc, loc_x, N_LOC);
    k_bin<<<(N_EDGE + TILE - 1) / TILE, 256, 0, stream>>>(ei, bucket_cnt, binned, N_EDGE);
    k_bscan<<<1, 512, 0, stream>>>(bucket_cnt, csr_off);
    k_bfill<<<NB, 256, 0, stream>>>(bucket_cnt, csr_off, binned, deg, row_ex, csr);
    k_aggr<<<N_LOC / 4, 256, 0, stream>>>(evtb, row_ex, deg, csr, meanb, N_LOC);
    k_comb<<<dense_grid, 256, 0, stream>>>(meanb, loc_x, W_l, b_l, W_r, W_h1, b_h1, W_h2, b_h2,
                                           out, N_LOC);
}

// Round 11
// 200.437 us; speedup vs baseline: 1.5845x; 1.0647x over previous
//
#include <hip/hip_runtime.h>

#define N_LOC 100000
#define N_EVT 100000
#define N_EDGE 1600000
#define NB 391        // ceil(N_LOC/256) buckets of 256 dst values
#define BCAP 5120     // bucket capacity: avg 4096 + 16 sigma
#define TILE 4096     // edges per k_bin block (256 thr x 16)
#define RBLK 64       // rows per block in dense kernels (4 waves x 16)

typedef short bf16x8 __attribute__((ext_vector_type(8)));
typedef float f32x4  __attribute__((ext_vector_type(4)));

__device__ __forceinline__ unsigned bf16_rne(float x) {
    unsigned u = __float_as_uint(x);
    return (u + 0x7fffu + ((u >> 16) & 1u)) >> 16;
}
__device__ __forceinline__ float bf_lo(unsigned u) { return __uint_as_float(u << 16); }
__device__ __forceinline__ float bf_hi(unsigned u) { return __uint_as_float(u & 0xffff0000u); }

// acc(cols 4cg..4cg+3) += av.{x,y,z,w} * W[4k4+{0,1,2,3}][cols]
#define DOT4(av, w0, w1, w2, w3, acc)                                           \
    acc.x = fmaf(av.x, w0.x, acc.x); acc.y = fmaf(av.x, w0.y, acc.y);           \
    acc.z = fmaf(av.x, w0.z, acc.z); acc.w = fmaf(av.x, w0.w, acc.w);           \
    acc.x = fmaf(av.y, w1.x, acc.x); acc.y = fmaf(av.y, w1.y, acc.y);           \
    acc.z = fmaf(av.y, w1.z, acc.z); acc.w = fmaf(av.y, w1.w, acc.w);           \
    acc.x = fmaf(av.z, w2.x, acc.x); acc.y = fmaf(av.z, w2.y, acc.y);           \
    acc.z = fmaf(av.z, w2.z, acc.z); acc.w = fmaf(av.z, w2.w, acc.w);           \
    acc.x = fmaf(av.w, w3.x, acc.x); acc.y = fmaf(av.w, w3.y, acc.y);           \
    acc.z = fmaf(av.w, w3.z, acc.z); acc.w = fmaf(av.w, w3.w, acc.w);

// ---------------------------------------------------------------------------
// K1 (MFMA): evt_x = relu(evt_feat @ W_evt + b_evt) -> bf16 u16 [N_EVT x 64]
// A staged bf16 [64][136] (row=r, k contiguous); W staged transposed bf16
// Wt[col][k] so the B-fragment (col=lane&15, k=(lane>>4)*8+i) is one b128.
// Per wave: 4 K-steps x (1 A-read + 4 B-reads + 4 MFMA). C/D per m89:
// col=lane&15, row=(lane>>4)*4+reg.  LDS 34.8 KB -> 4 blocks/CU.
// ---------------------------------------------------------------------------
__global__ __launch_bounds__(256) void k_evt(const float* __restrict__ feat,
                                             const float* __restrict__ W,
                                             const float* __restrict__ b,
                                             unsigned short* __restrict__ outb, int n) {
    __shared__ unsigned short sA[64 * 136];  // 17.4 KB (stride 272 B)
    __shared__ unsigned short sB[64 * 136];  // 17.4 KB, Wt[col][k]
    const int t = threadIdx.x;
    const int gbase = blockIdx.x * RBLK;
    // stage W transposed: read W[k][c] fp32 coalesced, pack k-pairs
    for (int idx = t; idx < 4096; idx += 256) {
        int kp = idx >> 6, c = idx & 63;
        float w0 = W[(2 * kp + 0) * 64 + c];
        float w1 = W[(2 * kp + 1) * 64 + c];
        *(unsigned*)&sB[c * 136 + 2 * kp] = bf16_rne(w0) | (bf16_rne(w1) << 16);
    }
    // stage A rows: float4 coalesced -> bf16x4
    for (int idx = t; idx < RBLK * 32; idx += 256) {
        int row = idx >> 5, c4 = idx & 31;
        int grow = gbase + row;
        float4 v = (grow < n) ? ((const float4*)feat)[(size_t)grow * 32 + c4]
                              : make_float4(0.f, 0.f, 0.f, 0.f);
        uint2 p = make_uint2(bf16_rne(v.x) | (bf16_rne(v.y) << 16),
                             bf16_rne(v.z) | (bf16_rne(v.w) << 16));
        *(uint2*)&sA[row * 136 + c4 * 4] = p;
    }
    __syncthreads();
    const int lane = t & 63;
    const int w = t >> 6;
    const int colL = lane & 15;   // col within tile; also A-row within stripe
    const int kq = lane >> 4;     // k-quad selector
    f32x4 acc0 = {0.f, 0.f, 0.f, 0.f}, acc1 = acc0, acc2 = acc0, acc3 = acc0;
#pragma unroll
    for (int s = 0; s < 4; ++s) {
        const int kb = s * 32 + kq * 8;
        bf16x8 a  = *(const bf16x8*)&sA[(16 * w + colL) * 136 + kb];
        bf16x8 b0 = *(const bf16x8*)&sB[(colL +  0) * 136 + kb];
        bf16x8 b1 = *(const bf16x8*)&sB[(colL + 16) * 136 + kb];
        bf16x8 b2 = *(const bf16x8*)&sB[(colL + 32) * 136 + kb];
        bf16x8 b3 = *(const bf16x8*)&sB[(colL + 48) * 136 + kb];
        acc0 = __builtin_amdgcn_mfma_f32_16x16x32_bf16(a, b0, acc0, 0, 0, 0);
        acc1 = __builtin_amdgcn_mfma_f32_16x16x32_bf16(a, b1, acc1, 0, 0, 0);
        acc2 = __builtin_amdgcn_mfma_f32_16x16x32_bf16(a, b2, acc2, 0, 0, 0);
        acc3 = __builtin_amdgcn_mfma_f32_16x16x32_bf16(a, b3, acc3, 0, 0, 0);
    }
    const float bias0 = b[colL +  0];
    const float bias1 = b[colL + 16];
    const float bias2 = b[colL + 32];
    const float bias3 = b[colL + 48];
    const int rbase = gbase + 16 * w + kq * 4;
#pragma unroll
    for (int j = 0; j < 4; ++j) {
        int grow = rbase + j;
        if (grow < n) {
            size_t o = (size_t)grow * 64;
            outb[o + colL +  0] = (unsigned short)bf16_rne(fmaxf(acc0[j] + bias0, 0.f));
            outb[o + colL + 16] = (unsigned short)bf16_rne(fmaxf(acc1[j] + bias1, 0.f));
            outb[o + colL + 32] = (unsigned short)bf16_rne(fmaxf(acc2[j] + bias2, 0.f));
            outb[o + colL + 48] = (unsigned short)bf16_rne(fmaxf(acc3[j] + bias3, 0.f));
        }
    }
}

// ---------------------------------------------------------------------------
// K2: loc_x = relu([loc_feat || emb[qid]] @ W_loc + b_loc)  [N_LOC x 64] fp32
// (unchanged from round 10)
// ---------------------------------------------------------------------------
__global__ __launch_bounds__(256) void k_loc(const float* __restrict__ feat,
                                             const int* __restrict__ qid,
                                             const float* __restrict__ emb,
                                             const float* __restrict__ W,
                                             const float* __restrict__ b,
                                             float* __restrict__ out, int n) {
    __shared__ float sW[144 * 64];    // 36 KB
    __shared__ float sA[RBLK * 136];  // 34.8 KB
    __shared__ float sE[RBLK * 20];   // 5.1 KB
    float4* sW4 = (float4*)sW;
    float4* sA4 = (float4*)sA;
    float4* sE4 = (float4*)sE;
    const int t = threadIdx.x;
    const int gbase = blockIdx.x * RBLK;
    for (int idx = t; idx < 2304; idx += 256) sW4[idx] = ((const float4*)W)[idx];
    for (int idx = t; idx < RBLK * 32; idx += 256) {
        int row = idx >> 5, c4 = idx & 31;
        int grow = gbase + row;
        sA4[row * 34 + c4] = (grow < n) ? ((const float4*)feat)[(size_t)grow * 32 + c4]
                                        : make_float4(0.f, 0.f, 0.f, 0.f);
    }
    for (int idx = t; idx < RBLK * 4; idx += 256) {
        int row = idx >> 2, e4 = idx & 3;
        int grow = gbase + row;
        int q = (grow < n) ? qid[grow] : 0;
        sE4[row * 5 + e4] = ((const float4*)emb)[(size_t)q * 4 + e4];
    }
    __syncthreads();
    const int lane = t & 63;
    const int w = t >> 6;
    const int cg = lane & 15;
    const int rg = lane >> 4;
    const int rbase = w * 16 + rg * 4;
    const float4 bias = ((const float4*)b)[cg];
    float4 a0 = bias, a1 = bias, a2 = bias, a3 = bias;
#pragma unroll 2
    for (int k4 = 0; k4 < 32; ++k4) {
        float4 w0 = sW4[(4 * k4 + 0) * 16 + cg];
        float4 w1 = sW4[(4 * k4 + 1) * 16 + cg];
        float4 w2 = sW4[(4 * k4 + 2) * 16 + cg];
        float4 w3 = sW4[(4 * k4 + 3) * 16 + cg];
        float4 v0 = sA4[(rbase + 0) * 34 + k4];
        float4 v1 = sA4[(rbase + 1) * 34 + k4];
        float4 v2 = sA4[(rbase + 2) * 34 + k4];
        float4 v3 = sA4[(rbase + 3) * 34 + k4];
        DOT4(v0, w0, w1, w2, w3, a0)
        DOT4(v1, w0, w1, w2, w3, a1)
        DOT4(v2, w0, w1, w2, w3, a2)
        DOT4(v3, w0, w1, w2, w3, a3)
    }
#pragma unroll
    for (int k4 = 0; k4 < 4; ++k4) {  // embedding tail, k = 128..143
        float4 w0 = sW4[(128 + 4 * k4 + 0) * 16 + cg];
        float4 w1 = sW4[(128 + 4 * k4 + 1) * 16 + cg];
        float4 w2 = sW4[(128 + 4 * k4 + 2) * 16 + cg];
        float4 w3 = sW4[(128 + 4 * k4 + 3) * 16 + cg];
        float4 v0 = sE4[(rbase + 0) * 5 + k4];
        float4 v1 = sE4[(rbase + 1) * 5 + k4];
        float4 v2 = sE4[(rbase + 2) * 5 + k4];
        float4 v3 = sE4[(rbase + 3) * 5 + k4];
        DOT4(v0, w0, w1, w2, w3, a0)
        DOT4(v1, w0, w1, w2, w3, a1)
        DOT4(v2, w0, w1, w2, w3, a2)
        DOT4(v3, w0, w1, w2, w3, a3)
    }
#define LOC_ST(j, acc)                                                          \
    {                                                                           \
        int grow = gbase + rbase + j;                                           \
        if (grow < n) {                                                         \
            float4 r = make_float4(fmaxf(acc.x, 0.f), fmaxf(acc.y, 0.f),        \
                                   fmaxf(acc.z, 0.f), fmaxf(acc.w, 0.f));       \
            ((float4*)out)[(size_t)grow * 16 + cg] = r;                         \
        }                                                                       \
    }
    LOC_ST(0, a0) LOC_ST(1, a1) LOC_ST(2, a2) LOC_ST(3, a3)
#undef LOC_ST
}

// ---------------------------------------------------------------------------
// k_bin: bucket edges by dst>>8; payload packed to 4B: src(24b) | dstlow(8b).
// ---------------------------------------------------------------------------
__global__ __launch_bounds__(256) void k_bin(const int* __restrict__ ei,
                                             int* __restrict__ bucket_cnt,
                                             unsigned* __restrict__ binned, int n) {
    __shared__ int h[NB];
    __shared__ int base[NB];
    const int t = threadIdx.x;
    for (int i = t; i < NB; i += 256) h[i] = 0;
    __syncthreads();
    const int e0 = blockIdx.x * TILE;
    int src[16], dst[16], rnk[16];
#pragma unroll
    for (int j = 0; j < 16; ++j) {
        int e = e0 + j * 256 + t;
        if (e < n) {
            src[j] = ei[e];
            dst[j] = ei[n + e];
            rnk[j] = atomicAdd(&h[dst[j] >> 8], 1);
        }
    }
    __syncthreads();
    for (int i = t; i < NB; i += 256) {
        int c = h[i];
        base[i] = (c > 0) ? atomicAdd(&bucket_cnt[i], c) : 0;
    }
    __syncthreads();
#pragma unroll
    for (int j = 0; j < 16; ++j) {
        int e = e0 + j * 256 + t;
        if (e < n) {
            int bk = dst[j] >> 8;
            int idx = base[bk] + rnk[j];
            if (idx < BCAP)
                binned[(size_t)bk * BCAP + idx] =
                    (unsigned)src[j] | ((unsigned)(dst[j] & 255) << 24);
        }
    }
}

// ---------------------------------------------------------------------------
// k_bscan: exclusive scan of the 391 bucket counts (single block).
// ---------------------------------------------------------------------------
__global__ __launch_bounds__(512) void k_bscan(const int* __restrict__ bucket_cnt,
                                               int* __restrict__ csr_off) {
    __shared__ int sd[512];
    const int t = threadIdx.x;
    int v = (t < NB) ? min(bucket_cnt[t], BCAP) : 0;
    sd[t] = v;
    __syncthreads();
    for (int off = 1; off < 512; off <<= 1) {
        int x = (t >= off) ? sd[t - off] : 0;
        __syncthreads();
        sd[t] += x;
        __syncthreads();
    }
    if (t < NB) csr_off[t] = sd[t] - v;
    if (t == NB - 1) csr_off[NB] = sd[t];
}

// ---------------------------------------------------------------------------
// k_bfill: one block per bucket: LDS degree hist -> scan -> deg/row_ex, then
// scatter csr with LDS cursors (writes confined to ~16KB window).
// ---------------------------------------------------------------------------
__global__ __launch_bounds__(256) void k_bfill(const int* __restrict__ bucket_cnt,
                                               const int* __restrict__ csr_off,
                                               const unsigned* __restrict__ binned,
                                               int* __restrict__ deg,
                                               int* __restrict__ row_ex,
                                               int* __restrict__ csr) {
    __shared__ int degl[256];
    __shared__ int sc[256];
    __shared__ int cur[256];
    const int b = blockIdx.x;
    const int t = threadIdx.x;
    const int nb = min(bucket_cnt[b], BCAP);
    const unsigned* bin = binned + (size_t)b * BCAP;
    degl[t] = 0;
    __syncthreads();
    for (int i = t; i < nb; i += 256)
        atomicAdd(&degl[bin[i] >> 24], 1);
    __syncthreads();
    const int v = degl[t];
    sc[t] = v;
    __syncthreads();
    for (int off = 1; off < 256; off <<= 1) {
        int x = (t >= off) ? sc[t - off] : 0;
        __syncthreads();
        sc[t] += x;
        __syncthreads();
    }
    const int ex = csr_off[b] + sc[t] - v;
    const int loc = b * 256 + t;
    if (loc < N_LOC) { deg[loc] = v; row_ex[loc] = ex; }
    cur[t] = ex;
    __syncthreads();
    for (int i = t; i < nb; i += 256) {
        unsigned u = bin[i];
        int pos = atomicAdd(&cur[u >> 24], 1);
        csr[pos] = (int)(u & 0x00FFFFFFu);
    }
}

// ---------------------------------------------------------------------------
// K4: mean[loc] from bf16-packed evt rows. One wave per loc. No LDS, lean
// VGPRs, launch_bounds(256,8) -> full occupancy for the latency-bound gather.
// ---------------------------------------------------------------------------
__global__ __launch_bounds__(256, 8) void k_aggr(const unsigned* __restrict__ evtb,
                                                 const int* __restrict__ row_ex,
                                                 const int* __restrict__ deg,
                                                 const int* __restrict__ csr,
                                                 float* __restrict__ meanb, int n) {
    const int lane = threadIdx.x & 63;
    const int wid = (blockIdx.x * 256 + threadIdx.x) >> 6;
    if (wid >= n) return;
    const int beg = row_ex[wid];
    const int cnt = deg[wid];
    const int half = lane >> 5;
    const int c = lane & 31;
    float a0 = 0.0f, a1 = 0.0f;
    int i = 0;
    for (; i + 8 <= cnt; i += 8) {
        const int bb = beg + i + half;
        int s0 = csr[bb + 0];
        int s1 = csr[bb + 2];
        int s2 = csr[bb + 4];
        int s3 = csr[bb + 6];
        unsigned u0 = evtb[(size_t)s0 * 32 + c];
        unsigned u1 = evtb[(size_t)s1 * 32 + c];
        unsigned u2 = evtb[(size_t)s2 * 32 + c];
        unsigned u3 = evtb[(size_t)s3 * 32 + c];
        a0 += (bf_lo(u0) + bf_lo(u1)) + (bf_lo(u2) + bf_lo(u3));
        a1 += (bf_hi(u0) + bf_hi(u1)) + (bf_hi(u2) + bf_hi(u3));
    }
    for (; i < cnt; i += 2) {
        int idx = i + half;
        if (idx < cnt) {
            int s = csr[beg + idx];
            unsigned u = evtb[(size_t)s * 32 + c];
            a0 += bf_lo(u);
            a1 += bf_hi(u);
        }
    }
    a0 += __shfl_xor(a0, 32);
    a1 += __shfl_xor(a1, 32);
    const float inv = 1.0f / (float)max(cnt, 1);
    if (lane < 32) {
        float2 mv = make_float2(a0 * inv, a1 * inv);
        *((float2*)(meanb + (size_t)wid * 64 + 2 * c)) = mv;
    }
}

// ---------------------------------------------------------------------------
// K5: x2 = relu([mean||locx] @ [W_l;W_r] + b_l); h = relu(x2 @ W_h1 + b_h1);
//     out = h @ W_h2 + b_h2.  (unchanged from round 10)
// ---------------------------------------------------------------------------
__global__ __launch_bounds__(256) void k_comb(
    const float* __restrict__ meanb, const float* __restrict__ locx,
    const float* __restrict__ W_l, const float* __restrict__ b_l,
    const float* __restrict__ W_r,
    const float* __restrict__ W_h1, const float* __restrict__ b_h1,
    const float* __restrict__ W_h2, const float* __restrict__ b_h2,
    float* __restrict__ out, int n)
{
    __shared__ float sWc[128 * 64];   // 32 KB: rows 0..63 = W_l, 64..127 = W_r
    __shared__ float sAB[RBLK * 136]; // 34.8 KB: cols 0..63 mean, 64..127 locx
    __shared__ float sWh1[64 * 32];   // 8 KB
    float4* sWc4 = (float4*)sWc;
    float4* sAB4 = (float4*)sAB;
    float4* sWh14 = (float4*)sWh1;
    const int t = threadIdx.x;
    const int gbase = blockIdx.x * RBLK;
    for (int idx = t; idx < 2048; idx += 256)
        sWc4[idx] = (idx < 1024) ? ((const float4*)W_l)[idx] : ((const float4*)W_r)[idx - 1024];
    for (int idx = t; idx < 512; idx += 256) sWh14[idx] = ((const float4*)W_h1)[idx];
    for (int idx = t; idx < RBLK * 16; idx += 256) {
        int row = idx >> 4, c4 = idx & 15;
        int grow = gbase + row;
        float4 mz = make_float4(0.f, 0.f, 0.f, 0.f);
        sAB4[row * 34 + c4]      = (grow < n) ? ((const float4*)meanb)[(size_t)grow * 16 + c4] : mz;
        sAB4[row * 34 + 16 + c4] = (grow < n) ? ((const float4*)locx)[(size_t)grow * 16 + c4] : mz;
    }
    __syncthreads();
    const int lane = t & 63;
    const int w = t >> 6;
    // ---- layer 1 ----
    {
        const int cg = lane & 15;
        const int rg = lane >> 4;
        const int rbase = w * 16 + rg * 4;
        const float4 bias = ((const float4*)b_l)[cg];
        float4 a0 = bias, a1 = bias, a2 = bias, a3 = bias;
#pragma unroll 2
        for (int k4 = 0; k4 < 32; ++k4) {
            float4 w0 = sWc4[(4 * k4 + 0) * 16 + cg];
            float4 w1 = sWc4[(4 * k4 + 1) * 16 + cg];
            float4 w2 = sWc4[(4 * k4 + 2) * 16 + cg];
            float4 w3 = sWc4[(4 * k4 + 3) * 16 + cg];
            float4 v0 = sAB4[(rbase + 0) * 34 + k4];
            float4 v1 = sAB4[(rbase + 1) * 34 + k4];
            float4 v2 = sAB4[(rbase + 2) * 34 + k4];
            float4 v3 = sAB4[(rbase + 3) * 34 + k4];
            DOT4(v0, w0, w1, w2, w3, a0)
            DOT4(v1, w0, w1, w2, w3, a1)
            DOT4(v2, w0, w1, w2, w3, a2)
            DOT4(v3, w0, w1, w2, w3, a3)
        }
        a0.x = fmaxf(a0.x, 0.f); a0.y = fmaxf(a0.y, 0.f); a0.z = fmaxf(a0.z, 0.f); a0.w = fmaxf(a0.w, 0.f);
        a1.x = fmaxf(a1.x, 0.f); a1.y = fmaxf(a1.y, 0.f); a1.z = fmaxf(a1.z, 0.f); a1.w = fmaxf(a1.w, 0.f);
        a2.x = fmaxf(a2.x, 0.f); a2.y = fmaxf(a2.y, 0.f); a2.z = fmaxf(a2.z, 0.f); a2.w = fmaxf(a2.w, 0.f);
        a3.x = fmaxf(a3.x, 0.f); a3.y = fmaxf(a3.y, 0.f); a3.z = fmaxf(a3.z, 0.f); a3.w = fmaxf(a3.w, 0.f);
        sAB4[(rbase + 0) * 34 + cg] = a0;
        sAB4[(rbase + 1) * 34 + cg] = a1;
        sAB4[(rbase + 2) * 34 + cg] = a2;
        sAB4[(rbase + 3) * 34 + cg] = a3;
    }
    // ---- layer 2 + head ----
    {
        const int cg2 = lane & 7;
        const int rg2 = lane >> 3;
        const int rbase = w * 16 + rg2 * 2;
        const float4 bias = ((const float4*)b_h1)[cg2];
        const float4 wh2 = ((const float4*)W_h2)[cg2];
        const float bh2 = b_h2[0];
        float4 h0 = bias, h1 = bias;
#pragma unroll 2
        for (int k4 = 0; k4 < 16; ++k4) {
            float4 w0 = sWh14[(4 * k4 + 0) * 8 + cg2];
            float4 w1 = sWh14[(4 * k4 + 1) * 8 + cg2];
            float4 w2 = sWh14[(4 * k4 + 2) * 8 + cg2];
            float4 w3 = sWh14[(4 * k4 + 3) * 8 + cg2];
            float4 v0 = sAB4[(rbase + 0) * 34 + k4];
            float4 v1 = sAB4[(rbase + 1) * 34 + k4];
            DOT4(v0, w0, w1, w2, w3, h0)
            DOT4(v1, w0, w1, w2, w3, h1)
        }
#pragma unroll
        for (int j = 0; j < 2; ++j) {
            float4 hh = (j == 0) ? h0 : h1;
            float p = fmaxf(hh.x, 0.f) * wh2.x + fmaxf(hh.y, 0.f) * wh2.y +
                      fmaxf(hh.z, 0.f) * wh2.z + fmaxf(hh.w, 0.f) * wh2.w;
            p += __shfl_xor(p, 1);
            p += __shfl_xor(p, 2);
            p += __shfl_xor(p, 4);
            int grow = gbase + rbase + j;
            if (cg2 == 0 && grow < n) out[grow] = p + bh2;
        }
    }
}

// ---------------------------------------------------------------------------
extern "C" void kernel_launch(void* const* d_in, const int* in_sizes, int n_in,
                              void* d_out, int out_size, void* d_ws, size_t ws_size,
                              hipStream_t stream) {
    const float* loc_feat = (const float*)d_in[0];
    const float* evt_feat = (const float*)d_in[1];
    const int*   qid      = (const int*)d_in[2];
    const int*   ei       = (const int*)d_in[3];
    const float* emb      = (const float*)d_in[4];
    const float* W_loc    = (const float*)d_in[5];
    const float* b_loc    = (const float*)d_in[6];
    const float* W_evt    = (const float*)d_in[7];
    const float* b_evt    = (const float*)d_in[8];
    const float* W_l      = (const float*)d_in[9];
    const float* b_l      = (const float*)d_in[10];
    const float* W_r      = (const float*)d_in[11];
    const float* W_h1     = (const float*)d_in[12];
    const float* b_h1     = (const float*)d_in[13];
    const float* W_h2     = (const float*)d_in[14];
    const float* b_h2     = (const float*)d_in[15];
    float* out = (float*)d_out;

    char* ws = (char*)d_ws;
    size_t off = 0;
    auto alloc = [&](size_t bytes) -> void* {
        void* p = ws + off;
        off += (bytes + 255) & ~(size_t)255;
        return p;
    };
    unsigned* evtb  = (unsigned*)alloc((size_t)N_EVT * 32 * 4);      // bf16 evt_x (12.8 MB)
    float* loc_x    = (float*)alloc((size_t)N_LOC * 64 * 4);         // 25.6 MB
    float* meanb    = (float*)alloc((size_t)N_LOC * 64 * 4);         // 25.6 MB
    unsigned* binned= (unsigned*)alloc((size_t)NB * BCAP * 4);       // 8 MB packed
    int*   deg      = (int*)alloc((size_t)N_LOC * 4);
    int*   row_ex   = (int*)alloc((size_t)(N_LOC + 1) * 4);
    int*   csr      = (int*)alloc((size_t)N_EDGE * 4);
    int*   bucket_cnt = (int*)alloc((size_t)NB * 4);
    int*   csr_off  = (int*)alloc((size_t)(NB + 1) * 4);
    (void)ws_size; (void)in_sizes; (void)n_in; (void)out_size;

    hipMemsetAsync(bucket_cnt, 0, (size_t)NB * 4, stream);

    const int dense_grid = (N_LOC + RBLK - 1) / RBLK;  // 1563
    k_evt<<<dense_grid, 256, 0, stream>>>(evt_feat, W_evt, b_evt,
                                          (unsigned short*)evtb, N_EVT);
    k_loc<<<dense_grid, 256, 0, stream>>>(loc_feat, qid, emb, W_loc, b_loc, loc_x, N_LOC);
    k_bin<<<(N_EDGE + TILE - 1) / TILE, 256, 0, stream>>>(ei, bucket_cnt, binned, N_EDGE);
    k_bscan<<<1, 512, 0, stream>>>(bucket_cnt, csr_off);
    k_bfill<<<NB, 256, 0, stream>>>(bucket_cnt, csr_off, binned, deg, row_ex, csr);
    k_aggr<<<N_LOC / 4, 256, 0, stream>>>(evtb, row_ex, deg, csr, meanb, N_LOC);
    k_comb<<<dense_grid, 256, 0, stream>>>(meanb, loc_x, W_l, b_l, W_r, W_h1, b_h1, W_h2, b_h2,
                                           out, N_LOC);
}

// Round 12
// 165.085 us; speedup vs baseline: 1.9238x; 1.2141x over previous
//
#include <hip/hip_runtime.h>

#define N_LOC 100000
#define N_EVT 100000
#define N_EDGE 1600000
#define NB 391        // ceil(N_LOC/256) buckets of 256 dst values
#define BCAP 5120     // bucket capacity: avg 4096 + 16 sigma
#define TILE 4096     // edges per k_bin block (256 thr x 16)
#define RBLK 64       // rows per block in dense kernels (4 waves x 16)

typedef short bf16x8 __attribute__((ext_vector_type(8)));
typedef float f32x4  __attribute__((ext_vector_type(4)));

__device__ __forceinline__ unsigned bf16_rne(float x) {
    unsigned u = __float_as_uint(x);
    return (u + 0x7fffu + ((u >> 16) & 1u)) >> 16;
}
__device__ __forceinline__ float bf_lo(unsigned u) { return __uint_as_float(u << 16); }
__device__ __forceinline__ float bf_hi(unsigned u) { return __uint_as_float(u & 0xffff0000u); }

// ---------------------------------------------------------------------------
// K1 (MFMA): evt_x = relu(evt_feat @ W_evt + b_evt) -> bf16 u16 [N_EVT x 64]
// (validated round 11)
// ---------------------------------------------------------------------------
__global__ __launch_bounds__(256) void k_evt(const float* __restrict__ feat,
                                             const float* __restrict__ W,
                                             const float* __restrict__ b,
                                             unsigned short* __restrict__ outb, int n) {
    __shared__ unsigned short sA[64 * 136];  // 17.4 KB
    __shared__ unsigned short sB[64 * 136];  // 17.4 KB, Wt[col][k]
    const int t = threadIdx.x;
    const int gbase = blockIdx.x * RBLK;
    for (int idx = t; idx < 4096; idx += 256) {
        int kp = idx >> 6, c = idx & 63;
        float w0 = W[(2 * kp + 0) * 64 + c];
        float w1 = W[(2 * kp + 1) * 64 + c];
        *(unsigned*)&sB[c * 136 + 2 * kp] = bf16_rne(w0) | (bf16_rne(w1) << 16);
    }
    for (int idx = t; idx < RBLK * 32; idx += 256) {
        int row = idx >> 5, c4 = idx & 31;
        int grow = gbase + row;
        float4 v = (grow < n) ? ((const float4*)feat)[(size_t)grow * 32 + c4]
                              : make_float4(0.f, 0.f, 0.f, 0.f);
        uint2 p = make_uint2(bf16_rne(v.x) | (bf16_rne(v.y) << 16),
                             bf16_rne(v.z) | (bf16_rne(v.w) << 16));
        *(uint2*)&sA[row * 136 + c4 * 4] = p;
    }
    __syncthreads();
    const int lane = t & 63;
    const int w = t >> 6;
    const int colL = lane & 15;
    const int kq = lane >> 4;
    f32x4 acc0 = {0.f, 0.f, 0.f, 0.f}, acc1 = acc0, acc2 = acc0, acc3 = acc0;
#pragma unroll
    for (int s = 0; s < 4; ++s) {
        const int kb = s * 32 + kq * 8;
        bf16x8 a  = *(const bf16x8*)&sA[(16 * w + colL) * 136 + kb];
        bf16x8 b0 = *(const bf16x8*)&sB[(colL +  0) * 136 + kb];
        bf16x8 b1 = *(const bf16x8*)&sB[(colL + 16) * 136 + kb];
        bf16x8 b2 = *(const bf16x8*)&sB[(colL + 32) * 136 + kb];
        bf16x8 b3 = *(const bf16x8*)&sB[(colL + 48) * 136 + kb];
        acc0 = __builtin_amdgcn_mfma_f32_16x16x32_bf16(a, b0, acc0, 0, 0, 0);
        acc1 = __builtin_amdgcn_mfma_f32_16x16x32_bf16(a, b1, acc1, 0, 0, 0);
        acc2 = __builtin_amdgcn_mfma_f32_16x16x32_bf16(a, b2, acc2, 0, 0, 0);
        acc3 = __builtin_amdgcn_mfma_f32_16x16x32_bf16(a, b3, acc3, 0, 0, 0);
    }
    const float bias0 = b[colL +  0];
    const float bias1 = b[colL + 16];
    const float bias2 = b[colL + 32];
    const float bias3 = b[colL + 48];
    const int rbase = gbase + 16 * w + kq * 4;
#pragma unroll
    for (int j = 0; j < 4; ++j) {
        int grow = rbase + j;
        if (grow < n) {
            size_t o = (size_t)grow * 64;
            outb[o + colL +  0] = (unsigned short)bf16_rne(fmaxf(acc0[j] + bias0, 0.f));
            outb[o + colL + 16] = (unsigned short)bf16_rne(fmaxf(acc1[j] + bias1, 0.f));
            outb[o + colL + 32] = (unsigned short)bf16_rne(fmaxf(acc2[j] + bias2, 0.f));
            outb[o + colL + 48] = (unsigned short)bf16_rne(fmaxf(acc3[j] + bias3, 0.f));
        }
    }
}

// ---------------------------------------------------------------------------
// K2 (MFMA): loc_x = relu([loc_feat || emb[qid]] @ W_loc + b_loc) -> bf16
// K padded 144->160 = 5 exact K-steps of 32; tail zeros in A and B.
// Output bf16 u16 [N_LOC x 64].
// ---------------------------------------------------------------------------
__global__ __launch_bounds__(256) void k_loc(const float* __restrict__ feat,
                                             const int* __restrict__ qid,
                                             const float* __restrict__ emb,
                                             const float* __restrict__ W,
                                             const float* __restrict__ b,
                                             unsigned short* __restrict__ outb, int n) {
    __shared__ unsigned short sA[64 * 168];  // 21.5 KB (160 k + 8 pad)
    __shared__ unsigned short sB[64 * 168];  // 21.5 KB, Wt[col][k]
    const int t = threadIdx.x;
    const int gbase = blockIdx.x * RBLK;
    // W (144x64) transposed, k-pairs; tail k=144..159 zero
    for (int idx = t; idx < 72 * 64; idx += 256) {
        int kp = idx >> 6, c = idx & 63;
        float w0 = W[(2 * kp + 0) * 64 + c];
        float w1 = W[(2 * kp + 1) * 64 + c];
        *(unsigned*)&sB[c * 168 + 2 * kp] = bf16_rne(w0) | (bf16_rne(w1) << 16);
    }
    for (int idx = t; idx < 64 * 2; idx += 256) {
        int c = idx >> 1, h = idx & 1;
        *(uint4*)&sB[c * 168 + 144 + h * 8] = make_uint4(0, 0, 0, 0);
    }
    // A rows: feat (k 0..127)
    for (int idx = t; idx < RBLK * 32; idx += 256) {
        int row = idx >> 5, c4 = idx & 31;
        int grow = gbase + row;
        float4 v = (grow < n) ? ((const float4*)feat)[(size_t)grow * 32 + c4]
                              : make_float4(0.f, 0.f, 0.f, 0.f);
        uint2 p = make_uint2(bf16_rne(v.x) | (bf16_rne(v.y) << 16),
                             bf16_rne(v.z) | (bf16_rne(v.w) << 16));
        *(uint2*)&sA[row * 168 + c4 * 4] = p;
    }
    // A rows: emb (k 128..143) + zero tail (k 144..159)
    for (int idx = t; idx < RBLK * 4; idx += 256) {
        int row = idx >> 2, e4 = idx & 3;
        int grow = gbase + row;
        int q = (grow < n) ? qid[grow] : 0;
        float4 v = ((const float4*)emb)[(size_t)q * 4 + e4];
        uint2 p = make_uint2(bf16_rne(v.x) | (bf16_rne(v.y) << 16),
                             bf16_rne(v.z) | (bf16_rne(v.w) << 16));
        *(uint2*)&sA[row * 168 + 128 + e4 * 4] = p;
    }
    for (int idx = t; idx < RBLK * 2; idx += 256) {
        int row = idx >> 1, h = idx & 1;
        *(uint4*)&sA[row * 168 + 144 + h * 8] = make_uint4(0, 0, 0, 0);
    }
    __syncthreads();
    const int lane = t & 63;
    const int w = t >> 6;
    const int colL = lane & 15;
    const int kq = lane >> 4;
    f32x4 acc0 = {0.f, 0.f, 0.f, 0.f}, acc1 = acc0, acc2 = acc0, acc3 = acc0;
#pragma unroll
    for (int s = 0; s < 5; ++s) {
        const int kb = s * 32 + kq * 8;
        bf16x8 a  = *(const bf16x8*)&sA[(16 * w + colL) * 168 + kb];
        bf16x8 b0 = *(const bf16x8*)&sB[(colL +  0) * 168 + kb];
        bf16x8 b1 = *(const bf16x8*)&sB[(colL + 16) * 168 + kb];
        bf16x8 b2 = *(const bf16x8*)&sB[(colL + 32) * 168 + kb];
        bf16x8 b3 = *(const bf16x8*)&sB[(colL + 48) * 168 + kb];
        acc0 = __builtin_amdgcn_mfma_f32_16x16x32_bf16(a, b0, acc0, 0, 0, 0);
        acc1 = __builtin_amdgcn_mfma_f32_16x16x32_bf16(a, b1, acc1, 0, 0, 0);
        acc2 = __builtin_amdgcn_mfma_f32_16x16x32_bf16(a, b2, acc2, 0, 0, 0);
        acc3 = __builtin_amdgcn_mfma_f32_16x16x32_bf16(a, b3, acc3, 0, 0, 0);
    }
    const float bias0 = b[colL +  0];
    const float bias1 = b[colL + 16];
    const float bias2 = b[colL + 32];
    const float bias3 = b[colL + 48];
    const int rbase = gbase + 16 * w + kq * 4;
#pragma unroll
    for (int j = 0; j < 4; ++j) {
        int grow = rbase + j;
        if (grow < n) {
            size_t o = (size_t)grow * 64;
            outb[o + colL +  0] = (unsigned short)bf16_rne(fmaxf(acc0[j] + bias0, 0.f));
            outb[o + colL + 16] = (unsigned short)bf16_rne(fmaxf(acc1[j] + bias1, 0.f));
            outb[o + colL + 32] = (unsigned short)bf16_rne(fmaxf(acc2[j] + bias2, 0.f));
            outb[o + colL + 48] = (unsigned short)bf16_rne(fmaxf(acc3[j] + bias3, 0.f));
        }
    }
}

// ---------------------------------------------------------------------------
// k_bin: bucket edges by dst>>8; payload packed to 4B: src(24b) | dstlow(8b).
// ---------------------------------------------------------------------------
__global__ __launch_bounds__(256) void k_bin(const int* __restrict__ ei,
                                             int* __restrict__ bucket_cnt,
                                             unsigned* __restrict__ binned, int n) {
    __shared__ int h[NB];
    __shared__ int base[NB];
    const int t = threadIdx.x;
    for (int i = t; i < NB; i += 256) h[i] = 0;
    __syncthreads();
    const int e0 = blockIdx.x * TILE;
    int src[16], dst[16], rnk[16];
#pragma unroll
    for (int j = 0; j < 16; ++j) {
        int e = e0 + j * 256 + t;
        if (e < n) {
            src[j] = ei[e];
            dst[j] = ei[n + e];
            rnk[j] = atomicAdd(&h[dst[j] >> 8], 1);
        }
    }
    __syncthreads();
    for (int i = t; i < NB; i += 256) {
        int c = h[i];
        base[i] = (c > 0) ? atomicAdd(&bucket_cnt[i], c) : 0;
    }
    __syncthreads();
#pragma unroll
    for (int j = 0; j < 16; ++j) {
        int e = e0 + j * 256 + t;
        if (e < n) {
            int bk = dst[j] >> 8;
            int idx = base[bk] + rnk[j];
            if (idx < BCAP)
                binned[(size_t)bk * BCAP + idx] =
                    (unsigned)src[j] | ((unsigned)(dst[j] & 255) << 24);
        }
    }
}

// ---------------------------------------------------------------------------
// k_bscan: exclusive scan of the 391 bucket counts (single block).
// ---------------------------------------------------------------------------
__global__ __launch_bounds__(512) void k_bscan(const int* __restrict__ bucket_cnt,
                                               int* __restrict__ csr_off) {
    __shared__ int sd[512];
    const int t = threadIdx.x;
    int v = (t < NB) ? min(bucket_cnt[t], BCAP) : 0;
    sd[t] = v;
    __syncthreads();
    for (int off = 1; off < 512; off <<= 1) {
        int x = (t >= off) ? sd[t - off] : 0;
        __syncthreads();
        sd[t] += x;
        __syncthreads();
    }
    if (t < NB) csr_off[t] = sd[t] - v;
    if (t == NB - 1) csr_off[NB] = sd[t];
}

// ---------------------------------------------------------------------------
// k_bfill: one block per bucket: LDS degree hist -> scan -> deg/row_ex, then
// scatter csr with LDS cursors (writes confined to ~16KB window).
// ---------------------------------------------------------------------------
__global__ __launch_bounds__(256) void k_bfill(const int* __restrict__ bucket_cnt,
                                               const int* __restrict__ csr_off,
                                               const unsigned* __restrict__ binned,
                                               int* __restrict__ deg,
                                               int* __restrict__ row_ex,
                                               int* __restrict__ csr) {
    __shared__ int degl[256];
    __shared__ int sc[256];
    __shared__ int cur[256];
    const int b = blockIdx.x;
    const int t = threadIdx.x;
    const int nb = min(bucket_cnt[b], BCAP);
    const unsigned* bin = binned + (size_t)b * BCAP;
    degl[t] = 0;
    __syncthreads();
    for (int i = t; i < nb; i += 256)
        atomicAdd(&degl[bin[i] >> 24], 1);
    __syncthreads();
    const int v = degl[t];
    sc[t] = v;
    __syncthreads();
    for (int off = 1; off < 256; off <<= 1) {
        int x = (t >= off) ? sc[t - off] : 0;
        __syncthreads();
        sc[t] += x;
        __syncthreads();
    }
    const int ex = csr_off[b] + sc[t] - v;
    const int loc = b * 256 + t;
    if (loc < N_LOC) { deg[loc] = v; row_ex[loc] = ex; }
    cur[t] = ex;
    __syncthreads();
    for (int i = t; i < nb; i += 256) {
        unsigned u = bin[i];
        int pos = atomicAdd(&cur[u >> 24], 1);
        csr[pos] = (int)(u & 0x00FFFFFFu);
    }
}

// ---------------------------------------------------------------------------
// K4: mean[loc] from bf16-packed evt rows -> bf16-packed mean [N_LOC x 32 u32]
// fp32 accumulate, bf16 pack at the end (halves the write traffic).
// ---------------------------------------------------------------------------
__global__ __launch_bounds__(256, 8) void k_aggr(const unsigned* __restrict__ evtb,
                                                 const int* __restrict__ row_ex,
                                                 const int* __restrict__ deg,
                                                 const int* __restrict__ csr,
                                                 unsigned* __restrict__ meanb, int n) {
    const int lane = threadIdx.x & 63;
    const int wid = (blockIdx.x * 256 + threadIdx.x) >> 6;
    if (wid >= n) return;
    const int beg = row_ex[wid];
    const int cnt = deg[wid];
    const int half = lane >> 5;
    const int c = lane & 31;
    float a0 = 0.0f, a1 = 0.0f;
    int i = 0;
    for (; i + 8 <= cnt; i += 8) {
        const int bb = beg + i + half;
        int s0 = csr[bb + 0];
        int s1 = csr[bb + 2];
        int s2 = csr[bb + 4];
        int s3 = csr[bb + 6];
        unsigned u0 = evtb[(size_t)s0 * 32 + c];
        unsigned u1 = evtb[(size_t)s1 * 32 + c];
        unsigned u2 = evtb[(size_t)s2 * 32 + c];
        unsigned u3 = evtb[(size_t)s3 * 32 + c];
        a0 += (bf_lo(u0) + bf_lo(u1)) + (bf_lo(u2) + bf_lo(u3));
        a1 += (bf_hi(u0) + bf_hi(u1)) + (bf_hi(u2) + bf_hi(u3));
    }
    for (; i < cnt; i += 2) {
        int idx = i + half;
        if (idx < cnt) {
            int s = csr[beg + idx];
            unsigned u = evtb[(size_t)s * 32 + c];
            a0 += bf_lo(u);
            a1 += bf_hi(u);
        }
    }
    a0 += __shfl_xor(a0, 32);
    a1 += __shfl_xor(a1, 32);
    const float inv = 1.0f / (float)max(cnt, 1);
    if (lane < 32)
        meanb[(size_t)wid * 32 + c] = bf16_rne(a0 * inv) | (bf16_rne(a1 * inv) << 16);
}

// ---------------------------------------------------------------------------
// K5 (MFMA): x2 = relu([mean||locx] @ [W_l;W_r] + b_l);
//            h = relu(x2 @ W_h1 + b_h1); out = h @ W_h2 + b_h2.
// Layer 1: K=128 bf16 MFMA (16 MFMA/wave). x2 -> bf16 LDS (wave-private rows,
// no barrier). Layer 2: K=64, N=32 (4 MFMA/wave). Head: shfl reduce.
// ---------------------------------------------------------------------------
__global__ __launch_bounds__(256) void k_comb(
    const unsigned* __restrict__ meanb, const unsigned* __restrict__ locxb,
    const float* __restrict__ W_l, const float* __restrict__ b_l,
    const float* __restrict__ W_r,
    const float* __restrict__ W_h1, const float* __restrict__ b_h1,
    const float* __restrict__ W_h2, const float* __restrict__ b_h2,
    float* __restrict__ out, int n)
{
    __shared__ unsigned short sA[64 * 136];   // 17.4 KB: k 0..63 mean, 64..127 locx
    __shared__ unsigned short sBc[64 * 136];  // 17.4 KB: [W_l;W_r]t[col][k]
    __shared__ unsigned short sX[64 * 72];    // 9.2 KB: x2 bf16
    __shared__ unsigned short sBh[32 * 72];   // 4.6 KB: W_h1t[col][k]
    const int t = threadIdx.x;
    const int gbase = blockIdx.x * RBLK;
    // [W_l;W_r] transposed, k-pairs
    for (int idx = t; idx < 64 * 64; idx += 256) {
        int kp = idx >> 6, c = idx & 63;
        float w0, w1;
        if (kp < 32) { w0 = W_l[(2 * kp + 0) * 64 + c]; w1 = W_l[(2 * kp + 1) * 64 + c]; }
        else { w0 = W_r[(2 * kp - 64 + 0) * 64 + c]; w1 = W_r[(2 * kp - 64 + 1) * 64 + c]; }
        *(unsigned*)&sBc[c * 136 + 2 * kp] = bf16_rne(w0) | (bf16_rne(w1) << 16);
    }
    // W_h1 (64x32) transposed, k-pairs
    for (int idx = t; idx < 32 * 32; idx += 256) {
        int kp = idx >> 5, c = idx & 31;
        float w0 = W_h1[(2 * kp + 0) * 32 + c];
        float w1 = W_h1[(2 * kp + 1) * 32 + c];
        *(unsigned*)&sBh[c * 72 + 2 * kp] = bf16_rne(w0) | (bf16_rne(w1) << 16);
    }
    // A rows: mean (k 0..63) + locx (k 64..127), already bf16-packed
    for (int idx = t; idx < RBLK * 32; idx += 256) {
        int row = idx >> 5, q = idx & 31;
        int grow = gbase + row;
        uint2 p = make_uint2(0, 0);
        if (grow < n) {
            p = (q < 16) ? ((const uint2*)meanb)[(size_t)grow * 16 + q]
                         : ((const uint2*)locxb)[(size_t)grow * 16 + (q - 16)];
        }
        *(uint2*)&sA[row * 136 + q * 4] = p;
    }
    __syncthreads();
    const int lane = t & 63;
    const int w = t >> 6;
    const int colL = lane & 15;
    const int kq = lane >> 4;
    // ---- layer 1: MFMA over K=128, 4 col-tiles ----
    f32x4 acc0 = {0.f, 0.f, 0.f, 0.f}, acc1 = acc0, acc2 = acc0, acc3 = acc0;
#pragma unroll
    for (int s = 0; s < 4; ++s) {
        const int kb = s * 32 + kq * 8;
        bf16x8 a  = *(const bf16x8*)&sA[(16 * w + colL) * 136 + kb];
        bf16x8 b0 = *(const bf16x8*)&sBc[(colL +  0) * 136 + kb];
        bf16x8 b1 = *(const bf16x8*)&sBc[(colL + 16) * 136 + kb];
        bf16x8 b2 = *(const bf16x8*)&sBc[(colL + 32) * 136 + kb];
        bf16x8 b3 = *(const bf16x8*)&sBc[(colL + 48) * 136 + kb];
        acc0 = __builtin_amdgcn_mfma_f32_16x16x32_bf16(a, b0, acc0, 0, 0, 0);
        acc1 = __builtin_amdgcn_mfma_f32_16x16x32_bf16(a, b1, acc1, 0, 0, 0);
        acc2 = __builtin_amdgcn_mfma_f32_16x16x32_bf16(a, b2, acc2, 0, 0, 0);
        acc3 = __builtin_amdgcn_mfma_f32_16x16x32_bf16(a, b3, acc3, 0, 0, 0);
    }
    {
        const float bias0 = b_l[colL +  0];
        const float bias1 = b_l[colL + 16];
        const float bias2 = b_l[colL + 32];
        const float bias3 = b_l[colL + 48];
#pragma unroll
        for (int j = 0; j < 4; ++j) {
            int row = 16 * w + kq * 4 + j;
            sX[row * 72 + colL +  0] = (unsigned short)bf16_rne(fmaxf(acc0[j] + bias0, 0.f));
            sX[row * 72 + colL + 16] = (unsigned short)bf16_rne(fmaxf(acc1[j] + bias1, 0.f));
            sX[row * 72 + colL + 32] = (unsigned short)bf16_rne(fmaxf(acc2[j] + bias2, 0.f));
            sX[row * 72 + colL + 48] = (unsigned short)bf16_rne(fmaxf(acc3[j] + bias3, 0.f));
        }
    }
    // wave w wrote rows 16w..16w+15 and reads only those: no barrier needed.
    // ---- layer 2: K=64, cols 0..31 (2 tiles) ----
    f32x4 h0 = {0.f, 0.f, 0.f, 0.f}, h1 = h0;
#pragma unroll
    for (int s = 0; s < 2; ++s) {
        const int kb = s * 32 + kq * 8;
        bf16x8 a  = *(const bf16x8*)&sX[(16 * w + colL) * 72 + kb];
        bf16x8 b0 = *(const bf16x8*)&sBh[(colL +  0) * 72 + kb];
        bf16x8 b1 = *(const bf16x8*)&sBh[(colL + 16) * 72 + kb];
        h0 = __builtin_amdgcn_mfma_f32_16x16x32_bf16(a, b0, h0, 0, 0, 0);
        h1 = __builtin_amdgcn_mfma_f32_16x16x32_bf16(a, b1, h1, 0, 0, 0);
    }
    // ---- head: out = relu(h) @ W_h2 + b_h2 ----
    {
        const float bh1c0 = b_h1[colL];
        const float bh1c1 = b_h1[colL + 16];
        const float wh2c0 = W_h2[colL];
        const float wh2c1 = W_h2[colL + 16];
        const float bh2 = b_h2[0];
#pragma unroll
        for (int j = 0; j < 4; ++j) {
            float p = fmaxf(h0[j] + bh1c0, 0.f) * wh2c0 +
                      fmaxf(h1[j] + bh1c1, 0.f) * wh2c1;
            p += __shfl_xor(p, 1);
            p += __shfl_xor(p, 2);
            p += __shfl_xor(p, 4);
            p += __shfl_xor(p, 8);
            int grow = gbase + 16 * w + kq * 4 + j;
            if (colL == 0 && grow < n) out[grow] = p + bh2;
        }
    }
}

// ---------------------------------------------------------------------------
extern "C" void kernel_launch(void* const* d_in, const int* in_sizes, int n_in,
                              void* d_out, int out_size, void* d_ws, size_t ws_size,
                              hipStream_t stream) {
    const float* loc_feat = (const float*)d_in[0];
    const float* evt_feat = (const float*)d_in[1];
    const int*   qid      = (const int*)d_in[2];
    const int*   ei       = (const int*)d_in[3];
    const float* emb      = (const float*)d_in[4];
    const float* W_loc    = (const float*)d_in[5];
    const float* b_loc    = (const float*)d_in[6];
    const float* W_evt    = (const float*)d_in[7];
    const float* b_evt    = (const float*)d_in[8];
    const float* W_l      = (const float*)d_in[9];
    const float* b_l      = (const float*)d_in[10];
    const float* W_r      = (const float*)d_in[11];
    const float* W_h1     = (const float*)d_in[12];
    const float* b_h1     = (const float*)d_in[13];
    const float* W_h2     = (const float*)d_in[14];
    const float* b_h2     = (const float*)d_in[15];
    float* out = (float*)d_out;

    char* ws = (char*)d_ws;
    size_t off = 0;
    auto alloc = [&](size_t bytes) -> void* {
        void* p = ws + off;
        off += (bytes + 255) & ~(size_t)255;
        return p;
    };
    unsigned* evtb  = (unsigned*)alloc((size_t)N_EVT * 32 * 4);      // bf16 evt_x (12.8 MB)
    unsigned* locxb = (unsigned*)alloc((size_t)N_LOC * 32 * 4);      // bf16 loc_x (12.8 MB)
    unsigned* meanb = (unsigned*)alloc((size_t)N_LOC * 32 * 4);      // bf16 mean (12.8 MB)
    unsigned* binned= (unsigned*)alloc((size_t)NB * BCAP * 4);       // 8 MB packed
    int*   deg      = (int*)alloc((size_t)N_LOC * 4);
    int*   row_ex   = (int*)alloc((size_t)(N_LOC + 1) * 4);
    int*   csr      = (int*)alloc((size_t)N_EDGE * 4);
    int*   bucket_cnt = (int*)alloc((size_t)NB * 4);
    int*   csr_off  = (int*)alloc((size_t)(NB + 1) * 4);
    (void)ws_size; (void)in_sizes; (void)n_in; (void)out_size;

    hipMemsetAsync(bucket_cnt, 0, (size_t)NB * 4, stream);

    const int dense_grid = (N_LOC + RBLK - 1) / RBLK;  // 1563
    k_evt<<<dense_grid, 256, 0, stream>>>(evt_feat, W_evt, b_evt,
                                          (unsigned short*)evtb, N_EVT);
    k_loc<<<dense_grid, 256, 0, stream>>>(loc_feat, qid, emb, W_loc, b_loc,
                                          (unsigned short*)locxb, N_LOC);
    k_bin<<<(N_EDGE + TILE - 1) / TILE, 256, 0, stream>>>(ei, bucket_cnt, binned, N_EDGE);
    k_bscan<<<1, 512, 0, stream>>>(bucket_cnt, csr_off);
    k_bfill<<<NB, 256, 0, stream>>>(bucket_cnt, csr_off, binned, deg, row_ex, csr);
    k_aggr<<<N_LOC / 4, 256, 0, stream>>>(evtb, row_ex, deg, csr, meanb, N_LOC);
    k_comb<<<dense_grid, 256, 0, stream>>>(meanb, locxb, W_l, b_l, W_r,
                                           W_h1, b_h1, W_h2, b_h2, out, N_LOC);
}

// Round 14
// 150.358 us; speedup vs baseline: 2.1123x; 1.0979x over previous
//
#include <hip/hip_runtime.h>

#define N_LOC 100000
#define N_EVT 100000
#define N_EDGE 1600000
#define NB 391        // ceil(N_LOC/256) buckets of 256 dst values
#define BCAP 5120     // bucket edge capacity: avg 4096 + 16 sigma
#define BCAPP 9216    // padded csr capacity: BCAP + 256*16
#define TILE 4096     // edges per k_bin block (256 thr x 16)
#define RBLK 64       // rows per block in dense kernels (4 waves x 16)

typedef short bf16x8 __attribute__((ext_vector_type(8)));
typedef float f32x4  __attribute__((ext_vector_type(4)));

__device__ __forceinline__ unsigned bf16_rne(float x) {
    unsigned u = __float_as_uint(x);
    return (u + 0x7fffu + ((u >> 16) & 1u)) >> 16;
}
__device__ __forceinline__ float bf_lo(unsigned u) { return __uint_as_float(u << 16); }
__device__ __forceinline__ float bf_hi(unsigned u) { return __uint_as_float(u & 0xffff0000u); }

// ---------------------------------------------------------------------------
// K1 (MFMA): evt_x = relu(evt_feat @ W_evt + b_evt) -> bf16 u16 [N_EVT x 64]
// (validated round 11)
// ---------------------------------------------------------------------------
__global__ __launch_bounds__(256) void k_evt(const float* __restrict__ feat,
                                             const float* __restrict__ W,
                                             const float* __restrict__ b,
                                             unsigned short* __restrict__ outb, int n) {
    __shared__ unsigned short sA[64 * 136];  // 17.4 KB
    __shared__ unsigned short sB[64 * 136];  // 17.4 KB, Wt[col][k]
    const int t = threadIdx.x;
    const int gbase = blockIdx.x * RBLK;
    for (int idx = t; idx < 4096; idx += 256) {
        int kp = idx >> 6, c = idx & 63;
        float w0 = W[(2 * kp + 0) * 64 + c];
        float w1 = W[(2 * kp + 1) * 64 + c];
        *(unsigned*)&sB[c * 136 + 2 * kp] = bf16_rne(w0) | (bf16_rne(w1) << 16);
    }
    for (int idx = t; idx < RBLK * 32; idx += 256) {
        int row = idx >> 5, c4 = idx & 31;
        int grow = gbase + row;
        float4 v = (grow < n) ? ((const float4*)feat)[(size_t)grow * 32 + c4]
                              : make_float4(0.f, 0.f, 0.f, 0.f);
        uint2 p = make_uint2(bf16_rne(v.x) | (bf16_rne(v.y) << 16),
                             bf16_rne(v.z) | (bf16_rne(v.w) << 16));
        *(uint2*)&sA[row * 136 + c4 * 4] = p;
    }
    __syncthreads();
    const int lane = t & 63;
    const int w = t >> 6;
    const int colL = lane & 15;
    const int kq = lane >> 4;
    f32x4 acc0 = {0.f, 0.f, 0.f, 0.f}, acc1 = acc0, acc2 = acc0, acc3 = acc0;
#pragma unroll
    for (int s = 0; s < 4; ++s) {
        const int kb = s * 32 + kq * 8;
        bf16x8 a  = *(const bf16x8*)&sA[(16 * w + colL) * 136 + kb];
        bf16x8 b0 = *(const bf16x8*)&sB[(colL +  0) * 136 + kb];
        bf16x8 b1 = *(const bf16x8*)&sB[(colL + 16) * 136 + kb];
        bf16x8 b2 = *(const bf16x8*)&sB[(colL + 32) * 136 + kb];
        bf16x8 b3 = *(const bf16x8*)&sB[(colL + 48) * 136 + kb];
        acc0 = __builtin_amdgcn_mfma_f32_16x16x32_bf16(a, b0, acc0, 0, 0, 0);
        acc1 = __builtin_amdgcn_mfma_f32_16x16x32_bf16(a, b1, acc1, 0, 0, 0);
        acc2 = __builtin_amdgcn_mfma_f32_16x16x32_bf16(a, b2, acc2, 0, 0, 0);
        acc3 = __builtin_amdgcn_mfma_f32_16x16x32_bf16(a, b3, acc3, 0, 0, 0);
    }
    const float bias0 = b[colL +  0];
    const float bias1 = b[colL + 16];
    const float bias2 = b[colL + 32];
    const float bias3 = b[colL + 48];
    const int rbase = gbase + 16 * w + kq * 4;
#pragma unroll
    for (int j = 0; j < 4; ++j) {
        int grow = rbase + j;
        if (grow < n) {
            size_t o = (size_t)grow * 64;
            outb[o + colL +  0] = (unsigned short)bf16_rne(fmaxf(acc0[j] + bias0, 0.f));
            outb[o + colL + 16] = (unsigned short)bf16_rne(fmaxf(acc1[j] + bias1, 0.f));
            outb[o + colL + 32] = (unsigned short)bf16_rne(fmaxf(acc2[j] + bias2, 0.f));
            outb[o + colL + 48] = (unsigned short)bf16_rne(fmaxf(acc3[j] + bias3, 0.f));
        }
    }
}

// ---------------------------------------------------------------------------
// K2 (MFMA): loc_x = relu([loc_feat || emb[qid]] @ W_loc + b_loc) -> bf16
// K padded 144->160 = 5 exact K-steps of 32; tail zeros in A and B.
// ---------------------------------------------------------------------------
__global__ __launch_bounds__(256) void k_loc(const float* __restrict__ feat,
                                             const int* __restrict__ qid,
                                             const float* __restrict__ emb,
                                             const float* __restrict__ W,
                                             const float* __restrict__ b,
                                             unsigned short* __restrict__ outb, int n) {
    __shared__ unsigned short sA[64 * 168];  // 21.5 KB
    __shared__ unsigned short sB[64 * 168];  // 21.5 KB, Wt[col][k]
    const int t = threadIdx.x;
    const int gbase = blockIdx.x * RBLK;
    for (int idx = t; idx < 72 * 64; idx += 256) {
        int kp = idx >> 6, c = idx & 63;
        float w0 = W[(2 * kp + 0) * 64 + c];
        float w1 = W[(2 * kp + 1) * 64 + c];
        *(unsigned*)&sB[c * 168 + 2 * kp] = bf16_rne(w0) | (bf16_rne(w1) << 16);
    }
    for (int idx = t; idx < 64 * 2; idx += 256) {
        int c = idx >> 1, h = idx & 1;
        *(uint4*)&sB[c * 168 + 144 + h * 8] = make_uint4(0, 0, 0, 0);
    }
    for (int idx = t; idx < RBLK * 32; idx += 256) {
        int row = idx >> 5, c4 = idx & 31;
        int grow = gbase + row;
        float4 v = (grow < n) ? ((const float4*)feat)[(size_t)grow * 32 + c4]
                              : make_float4(0.f, 0.f, 0.f, 0.f);
        uint2 p = make_uint2(bf16_rne(v.x) | (bf16_rne(v.y) << 16),
                             bf16_rne(v.z) | (bf16_rne(v.w) << 16));
        *(uint2*)&sA[row * 168 + c4 * 4] = p;
    }
    for (int idx = t; idx < RBLK * 4; idx += 256) {
        int row = idx >> 2, e4 = idx & 3;
        int grow = gbase + row;
        int q = (grow < n) ? qid[grow] : 0;
        float4 v = ((const float4*)emb)[(size_t)q * 4 + e4];
        uint2 p = make_uint2(bf16_rne(v.x) | (bf16_rne(v.y) << 16),
                             bf16_rne(v.z) | (bf16_rne(v.w) << 16));
        *(uint2*)&sA[row * 168 + 128 + e4 * 4] = p;
    }
    for (int idx = t; idx < RBLK * 2; idx += 256) {
        int row = idx >> 1, h = idx & 1;
        *(uint4*)&sA[row * 168 + 144 + h * 8] = make_uint4(0, 0, 0, 0);
    }
    __syncthreads();
    const int lane = t & 63;
    const int w = t >> 6;
    const int colL = lane & 15;
    const int kq = lane >> 4;
    f32x4 acc0 = {0.f, 0.f, 0.f, 0.f}, acc1 = acc0, acc2 = acc0, acc3 = acc0;
#pragma unroll
    for (int s = 0; s < 5; ++s) {
        const int kb = s * 32 + kq * 8;
        bf16x8 a  = *(const bf16x8*)&sA[(16 * w + colL) * 168 + kb];
        bf16x8 b0 = *(const bf16x8*)&sB[(colL +  0) * 168 + kb];
        bf16x8 b1 = *(const bf16x8*)&sB[(colL + 16) * 168 + kb];
        bf16x8 b2 = *(const bf16x8*)&sB[(colL + 32) * 168 + kb];
        bf16x8 b3 = *(const bf16x8*)&sB[(colL + 48) * 168 + kb];
        acc0 = __builtin_amdgcn_mfma_f32_16x16x32_bf16(a, b0, acc0, 0, 0, 0);
        acc1 = __builtin_amdgcn_mfma_f32_16x16x32_bf16(a, b1, acc1, 0, 0, 0);
        acc2 = __builtin_amdgcn_mfma_f32_16x16x32_bf16(a, b2, acc2, 0, 0, 0);
        acc3 = __builtin_amdgcn_mfma_f32_16x16x32_bf16(a, b3, acc3, 0, 0, 0);
    }
    const float bias0 = b[colL +  0];
    const float bias1 = b[colL + 16];
    const float bias2 = b[colL + 32];
    const float bias3 = b[colL + 48];
    const int rbase = gbase + 16 * w + kq * 4;
#pragma unroll
    for (int j = 0; j < 4; ++j) {
        int grow = rbase + j;
        if (grow < n) {
            size_t o = (size_t)grow * 64;
            outb[o + colL +  0] = (unsigned short)bf16_rne(fmaxf(acc0[j] + bias0, 0.f));
            outb[o + colL + 16] = (unsigned short)bf16_rne(fmaxf(acc1[j] + bias1, 0.f));
            outb[o + colL + 32] = (unsigned short)bf16_rne(fmaxf(acc2[j] + bias2, 0.f));
            outb[o + colL + 48] = (unsigned short)bf16_rne(fmaxf(acc3[j] + bias3, 0.f));
        }
    }
}

// ---------------------------------------------------------------------------
// k_bin: bucket edges by dst>>8; payload packed to 4B: src(24b) | dstlow(8b).
// ---------------------------------------------------------------------------
__global__ __launch_bounds__(256) void k_bin(const int* __restrict__ ei,
                                             int* __restrict__ bucket_cnt,
                                             unsigned* __restrict__ binned, int n) {
    __shared__ int h[NB];
    __shared__ int base[NB];
    const int t = threadIdx.x;
    for (int i = t; i < NB; i += 256) h[i] = 0;
    __syncthreads();
    const int e0 = blockIdx.x * TILE;
    int src[16], dst[16], rnk[16];
#pragma unroll
    for (int j = 0; j < 16; ++j) {
        int e = e0 + j * 256 + t;
        if (e < n) {
            src[j] = ei[e];
            dst[j] = ei[n + e];
            rnk[j] = atomicAdd(&h[dst[j] >> 8], 1);
        }
    }
    __syncthreads();
    for (int i = t; i < NB; i += 256) {
        int c = h[i];
        base[i] = (c > 0) ? atomicAdd(&bucket_cnt[i], c) : 0;
    }
    __syncthreads();
#pragma unroll
    for (int j = 0; j < 16; ++j) {
        int e = e0 + j * 256 + t;
        if (e < n) {
            int bk = dst[j] >> 8;
            int idx = base[bk] + rnk[j];
            if (idx < BCAP)
                binned[(size_t)bk * BCAP + idx] =
                    (unsigned)src[j] | ((unsigned)(dst[j] & 255) << 24);
        }
    }
}

// ---------------------------------------------------------------------------
// k_bfill: one block per bucket. LDS degree hist -> scan of PADDED degrees
// (pad-to-16) -> deg/row_ex at fixed per-bucket csr stride BCAPP, then
// scatter csr with LDS cursors and fill pad slots with the dummy src N_EVT.
// (k_bscan eliminated: fixed bucket capacity makes bucket offsets static.)
// ---------------------------------------------------------------------------
__global__ __launch_bounds__(256) void k_bfill(const int* __restrict__ bucket_cnt,
                                               const unsigned* __restrict__ binned,
                                               int* __restrict__ deg,
                                               int* __restrict__ row_ex,
                                               int* __restrict__ csr) {
    __shared__ int degl[256];
    __shared__ int sc[256];
    __shared__ int cur[256];
    const int b = blockIdx.x;
    const int t = threadIdx.x;
    const int nb = min(bucket_cnt[b], BCAP);
    const unsigned* bin = binned + (size_t)b * BCAP;
    degl[t] = 0;
    __syncthreads();
    for (int i = t; i < nb; i += 256)
        atomicAdd(&degl[bin[i] >> 24], 1);
    __syncthreads();
    const int v = degl[t];
    const int vpad = (v + 15) & ~15;
    sc[t] = vpad;
    __syncthreads();
    for (int off = 1; off < 256; off <<= 1) {
        int x = (t >= off) ? sc[t - off] : 0;
        __syncthreads();
        sc[t] += x;
        __syncthreads();
    }
    const int ex = b * BCAPP + sc[t] - vpad;  // sum(vpad) <= 5120+3840 < BCAPP
    const int loc = b * 256 + t;
    if (loc < N_LOC) { deg[loc] = v; row_ex[loc] = ex; }
    cur[t] = ex;
    __syncthreads();
    for (int i = t; i < nb; i += 256) {
        unsigned u = bin[i];
        int pos = atomicAdd(&cur[u >> 24], 1);
        csr[pos] = (int)(u & 0x00FFFFFFu);
    }
    // pad slots -> dummy zero-row index (disjoint from scattered range)
    for (int j = v; j < vpad; ++j) csr[ex + j] = N_EVT;
}

// ---------------------------------------------------------------------------
// K4: mean[loc] from bf16-packed evt rows -> bf16-packed mean.
// Padded CSR (multiple of 16): tail-free loop, 8 csr loads + 8 gathers in
// flight per iteration. Dummy rows hit the L1-hot zero row.
// ---------------------------------------------------------------------------
__global__ __launch_bounds__(256, 8) void k_aggr(const unsigned* __restrict__ evtb,
                                                 const int* __restrict__ row_ex,
                                                 const int* __restrict__ deg,
                                                 const int* __restrict__ csr,
                                                 unsigned* __restrict__ meanb, int n) {
    const int lane = threadIdx.x & 63;
    int wid = (blockIdx.x * 256 + threadIdx.x) >> 6;
    wid = __builtin_amdgcn_readfirstlane(wid);
    if (wid >= n) return;
    const int beg = row_ex[wid];
    const int cnt = deg[wid];
    const int cntp = (cnt + 15) & ~15;
    const int half = lane >> 5;   // which edge of each pair
    const int c = lane & 31;      // channel-pair index
    float a0 = 0.0f, a1 = 0.0f;
    for (int i = 0; i < cntp; i += 16) {
        const int bb = beg + i + half;
        int s0 = csr[bb +  0];
        int s1 = csr[bb +  2];
        int s2 = csr[bb +  4];
        int s3 = csr[bb +  6];
        int s4 = csr[bb +  8];
        int s5 = csr[bb + 10];
        int s6 = csr[bb + 12];
        int s7 = csr[bb + 14];
        unsigned u0 = evtb[(size_t)s0 * 32 + c];
        unsigned u1 = evtb[(size_t)s1 * 32 + c];
        unsigned u2 = evtb[(size_t)s2 * 32 + c];
        unsigned u3 = evtb[(size_t)s3 * 32 + c];
        unsigned u4 = evtb[(size_t)s4 * 32 + c];
        unsigned u5 = evtb[(size_t)s5 * 32 + c];
        unsigned u6 = evtb[(size_t)s6 * 32 + c];
        unsigned u7 = evtb[(size_t)s7 * 32 + c];
        a0 += ((bf_lo(u0) + bf_lo(u1)) + (bf_lo(u2) + bf_lo(u3))) +
              ((bf_lo(u4) + bf_lo(u5)) + (bf_lo(u6) + bf_lo(u7)));
        a1 += ((bf_hi(u0) + bf_hi(u1)) + (bf_hi(u2) + bf_hi(u3))) +
              ((bf_hi(u4) + bf_hi(u5)) + (bf_hi(u6) + bf_hi(u7)));
    }
    a0 += __shfl_xor(a0, 32);
    a1 += __shfl_xor(a1, 32);
    const float inv = 1.0f / (float)max(cnt, 1);
    if (lane < 32)
        meanb[(size_t)wid * 32 + c] = bf16_rne(a0 * inv) | (bf16_rne(a1 * inv) << 16);
}

// ---------------------------------------------------------------------------
// K5 (MFMA): x2 = relu([mean||locx] @ [W_l;W_r] + b_l);
//            h = relu(x2 @ W_h1 + b_h1); out = h @ W_h2 + b_h2.
// (validated round 12)
// ---------------------------------------------------------------------------
__global__ __launch_bounds__(256) void k_comb(
    const unsigned* __restrict__ meanb, const unsigned* __restrict__ locxb,
    const float* __restrict__ W_l, const float* __restrict__ b_l,
    const float* __restrict__ W_r,
    const float* __restrict__ W_h1, const float* __restrict__ b_h1,
    const float* __restrict__ W_h2, const float* __restrict__ b_h2,
    float* __restrict__ out, int n)
{
    __shared__ unsigned short sA[64 * 136];
    __shared__ unsigned short sBc[64 * 136];
    __shared__ unsigned short sX[64 * 72];
    __shared__ unsigned short sBh[32 * 72];
    const int t = threadIdx.x;
    const int gbase = blockIdx.x * RBLK;
    for (int idx = t; idx < 64 * 64; idx += 256) {
        int kp = idx >> 6, c = idx & 63;
        float w0, w1;
        if (kp < 32) { w0 = W_l[(2 * kp + 0) * 64 + c]; w1 = W_l[(2 * kp + 1) * 64 + c]; }
        else { w0 = W_r[(2 * kp - 64 + 0) * 64 + c]; w1 = W_r[(2 * kp - 64 + 1) * 64 + c]; }
        *(unsigned*)&sBc[c * 136 + 2 * kp] = bf16_rne(w0) | (bf16_rne(w1) << 16);
    }
    for (int idx = t; idx < 32 * 32; idx += 256) {
        int kp = idx >> 5, c = idx & 31;
        float w0 = W_h1[(2 * kp + 0) * 32 + c];
        float w1 = W_h1[(2 * kp + 1) * 32 + c];
        *(unsigned*)&sBh[c * 72 + 2 * kp] = bf16_rne(w0) | (bf16_rne(w1) << 16);
    }
    for (int idx = t; idx < RBLK * 32; idx += 256) {
        int row = idx >> 5, q = idx & 31;
        int grow = gbase + row;
        uint2 p = make_uint2(0, 0);
        if (grow < n) {
            p = (q < 16) ? ((const uint2*)meanb)[(size_t)grow * 16 + q]
                         : ((const uint2*)locxb)[(size_t)grow * 16 + (q - 16)];
        }
        *(uint2*)&sA[row * 136 + q * 4] = p;
    }
    __syncthreads();
    const int lane = t & 63;
    const int w = t >> 6;
    const int colL = lane & 15;
    const int kq = lane >> 4;
    f32x4 acc0 = {0.f, 0.f, 0.f, 0.f}, acc1 = acc0, acc2 = acc0, acc3 = acc0;
#pragma unroll
    for (int s = 0; s < 4; ++s) {
        const int kb = s * 32 + kq * 8;
        bf16x8 a  = *(const bf16x8*)&sA[(16 * w + colL) * 136 + kb];
        bf16x8 b0 = *(const bf16x8*)&sBc[(colL +  0) * 136 + kb];
        bf16x8 b1 = *(const bf16x8*)&sBc[(colL + 16) * 136 + kb];
        bf16x8 b2 = *(const bf16x8*)&sBc[(colL + 32) * 136 + kb];
        bf16x8 b3 = *(const bf16x8*)&sBc[(colL + 48) * 136 + kb];
        acc0 = __builtin_amdgcn_mfma_f32_16x16x32_bf16(a, b0, acc0, 0, 0, 0);
        acc1 = __builtin_amdgcn_mfma_f32_16x16x32_bf16(a, b1, acc1, 0, 0, 0);
        acc2 = __builtin_amdgcn_mfma_f32_16x16x32_bf16(a, b2, acc2, 0, 0, 0);
        acc3 = __builtin_amdgcn_mfma_f32_16x16x32_bf16(a, b3, acc3, 0, 0, 0);
    }
    {
        const float bias0 = b_l[colL +  0];
        const float bias1 = b_l[colL + 16];
        const float bias2 = b_l[colL + 32];
        const float bias3 = b_l[colL + 48];
#pragma unroll
        for (int j = 0; j < 4; ++j) {
            int row = 16 * w + kq * 4 + j;
            sX[row * 72 + colL +  0] = (unsigned short)bf16_rne(fmaxf(acc0[j] + bias0, 0.f));
            sX[row * 72 + colL + 16] = (unsigned short)bf16_rne(fmaxf(acc1[j] + bias1, 0.f));
            sX[row * 72 + colL + 32] = (unsigned short)bf16_rne(fmaxf(acc2[j] + bias2, 0.f));
            sX[row * 72 + colL + 48] = (unsigned short)bf16_rne(fmaxf(acc3[j] + bias3, 0.f));
        }
    }
    // wave w wrote rows 16w..16w+15 and reads only those: no barrier needed.
    f32x4 h0 = {0.f, 0.f, 0.f, 0.f}, h1 = h0;
#pragma unroll
    for (int s = 0; s < 2; ++s) {
        const int kb = s * 32 + kq * 8;
        bf16x8 a  = *(const bf16x8*)&sX[(16 * w + colL) * 72 + kb];
        bf16x8 b0 = *(const bf16x8*)&sBh[(colL +  0) * 72 + kb];
        bf16x8 b1 = *(const bf16x8*)&sBh[(colL + 16) * 72 + kb];
        h0 = __builtin_amdgcn_mfma_f32_16x16x32_bf16(a, b0, h0, 0, 0, 0);
        h1 = __builtin_amdgcn_mfma_f32_16x16x32_bf16(a, b1, h1, 0, 0, 0);
    }
    {
        const float bh1c0 = b_h1[colL];
        const float bh1c1 = b_h1[colL + 16];
        const float wh2c0 = W_h2[colL];
        const float wh2c1 = W_h2[colL + 16];
        const float bh2 = b_h2[0];
#pragma unroll
        for (int j = 0; j < 4; ++j) {
            float p = fmaxf(h0[j] + bh1c0, 0.f) * wh2c0 +
                      fmaxf(h1[j] + bh1c1, 0.f) * wh2c1;
            p += __shfl_xor(p, 1);
            p += __shfl_xor(p, 2);
            p += __shfl_xor(p, 4);
            p += __shfl_xor(p, 8);
            int grow = gbase + 16 * w + kq * 4 + j;
            if (colL == 0 && grow < n) out[grow] = p + bh2;
        }
    }
}

// ---------------------------------------------------------------------------
extern "C" void kernel_launch(void* const* d_in, const int* in_sizes, int n_in,
                              void* d_out, int out_size, void* d_ws, size_t ws_size,
                              hipStream_t stream) {
    const float* loc_feat = (const float*)d_in[0];
    const float* evt_feat = (const float*)d_in[1];
    const int*   qid      = (const int*)d_in[2];
    const int*   ei       = (const int*)d_in[3];
    const float* emb      = (const float*)d_in[4];
    const float* W_loc    = (const float*)d_in[5];
    const float* b_loc    = (const float*)d_in[6];
    const float* W_evt    = (const float*)d_in[7];
    const float* b_evt    = (const float*)d_in[8];
    const float* W_l      = (const float*)d_in[9];
    const float* b_l      = (const float*)d_in[10];
    const float* W_r      = (const float*)d_in[11];
    const float* W_h1     = (const float*)d_in[12];
    const float* b_h1     = (const float*)d_in[13];
    const float* W_h2     = (const float*)d_in[14];
    const float* b_h2     = (const float*)d_in[15];
    float* out = (float*)d_out;

    char* ws = (char*)d_ws;
    size_t off = 0;
    auto alloc = [&](size_t bytes) -> void* {
        void* p = ws + off;
        off += (bytes + 255) & ~(size_t)255;
        return p;
    };
    unsigned* evtb  = (unsigned*)alloc((size_t)(N_EVT + 1) * 32 * 4); // bf16 evt_x + zero row
    unsigned* locxb = (unsigned*)alloc((size_t)N_LOC * 32 * 4);       // bf16 loc_x (12.8 MB)
    unsigned* meanb = (unsigned*)alloc((size_t)N_LOC * 32 * 4);       // bf16 mean (12.8 MB)
    unsigned* binned= (unsigned*)alloc((size_t)NB * BCAP * 4);        // 8 MB packed
    int*   deg      = (int*)alloc((size_t)N_LOC * 4);
    int*   row_ex   = (int*)alloc((size_t)(N_LOC + 1) * 4);
    int*   csr      = (int*)alloc((size_t)NB * BCAPP * 4);            // 14.4 MB padded
    int*   bucket_cnt = (int*)alloc((size_t)NB * 4);
    (void)ws_size; (void)in_sizes; (void)n_in; (void)out_size;

    hipMemsetAsync(bucket_cnt, 0, (size_t)NB * 4, stream);
    hipMemsetAsync(evtb + (size_t)N_EVT * 32, 0, 32 * 4, stream);  // dummy zero row

    const int dense_grid = (N_LOC + RBLK - 1) / RBLK;  // 1563
    k_evt<<<dense_grid, 256, 0, stream>>>(evt_feat, W_evt, b_evt,
                                          (unsigned short*)evtb, N_EVT);
    k_loc<<<dense_grid, 256, 0, stream>>>(loc_feat, qid, emb, W_loc, b_loc,
                                          (unsigned short*)locxb, N_LOC);
    k_bin<<<(N_EDGE + TILE - 1) / TILE, 256, 0, stream>>>(ei, bucket_cnt, binned, N_EDGE);
    k_bfill<<<NB, 256, 0, stream>>>(bucket_cnt, binned, deg, row_ex, csr);
    k_aggr<<<N_LOC / 4, 256, 0, stream>>>(evtb, row_ex, deg, csr, meanb, N_LOC);
    k_comb<<<dense_grid, 256, 0, stream>>>(meanb, locxb, W_l, b_l, W_r,
                                           W_h1, b_h1, W_h2, b_h2, out, N_LOC);
}

// Round 15
// 141.943 us; speedup vs baseline: 2.2375x; 1.0593x over previous
//
#include <hip/hip_runtime.h>

#define N_LOC 100000
#define N_EVT 100000
#define N_EDGE 1600000
#define NB 391        // ceil(N_LOC/256) buckets of 256 dst values
#define BCAP 5120     // bucket edge capacity: avg 4096 + 16 sigma
#define BCAPP 9216    // padded csr capacity: BCAP + 256*16
#define TILE 4096     // edges per k_bin block (256 thr x 16)
#define RBLK 64       // rows per block in dense kernels (4 waves x 16)

typedef short bf16x8 __attribute__((ext_vector_type(8)));
typedef float f32x4  __attribute__((ext_vector_type(4)));

__device__ __forceinline__ unsigned bf16_rne(float x) {
    unsigned u = __float_as_uint(x);
    return (u + 0x7fffu + ((u >> 16) & 1u)) >> 16;
}
__device__ __forceinline__ float bf_lo(unsigned u) { return __uint_as_float(u << 16); }
__device__ __forceinline__ float bf_hi(unsigned u) { return __uint_as_float(u & 0xffff0000u); }

// ---------------------------------------------------------------------------
// K1 (MFMA): evt_x = relu(evt_feat @ W_evt + b_evt) -> bf16 u16 [N_EVT x 64]
// Block 0 additionally zeroes bucket_cnt and the dummy evt row (replaces two
// ~38us rocclr fillBuffer dispatches; stream order makes this safe).
// ---------------------------------------------------------------------------
__global__ __launch_bounds__(256) void k_evt(const float* __restrict__ feat,
                                             const float* __restrict__ W,
                                             const float* __restrict__ b,
                                             unsigned short* __restrict__ outb,
                                             int* __restrict__ bucket_cnt,
                                             unsigned* __restrict__ dummy_row, int n) {
    __shared__ unsigned short sA[64 * 136];  // 17.4 KB
    __shared__ unsigned short sB[64 * 136];  // 17.4 KB, Wt[col][k]
    const int t = threadIdx.x;
    const int gbase = blockIdx.x * RBLK;
    if (blockIdx.x == 0) {
        for (int i = t; i < NB; i += 256) bucket_cnt[i] = 0;
        if (t < 32) dummy_row[t] = 0u;
    }
    for (int idx = t; idx < 4096; idx += 256) {
        int kp = idx >> 6, c = idx & 63;
        float w0 = W[(2 * kp + 0) * 64 + c];
        float w1 = W[(2 * kp + 1) * 64 + c];
        *(unsigned*)&sB[c * 136 + 2 * kp] = bf16_rne(w0) | (bf16_rne(w1) << 16);
    }
    for (int idx = t; idx < RBLK * 32; idx += 256) {
        int row = idx >> 5, c4 = idx & 31;
        int grow = gbase + row;
        float4 v = (grow < n) ? ((const float4*)feat)[(size_t)grow * 32 + c4]
                              : make_float4(0.f, 0.f, 0.f, 0.f);
        uint2 p = make_uint2(bf16_rne(v.x) | (bf16_rne(v.y) << 16),
                             bf16_rne(v.z) | (bf16_rne(v.w) << 16));
        *(uint2*)&sA[row * 136 + c4 * 4] = p;
    }
    __syncthreads();
    const int lane = t & 63;
    const int w = t >> 6;
    const int colL = lane & 15;
    const int kq = lane >> 4;
    f32x4 acc0 = {0.f, 0.f, 0.f, 0.f}, acc1 = acc0, acc2 = acc0, acc3 = acc0;
#pragma unroll
    for (int s = 0; s < 4; ++s) {
        const int kb = s * 32 + kq * 8;
        bf16x8 a  = *(const bf16x8*)&sA[(16 * w + colL) * 136 + kb];
        bf16x8 b0 = *(const bf16x8*)&sB[(colL +  0) * 136 + kb];
        bf16x8 b1 = *(const bf16x8*)&sB[(colL + 16) * 136 + kb];
        bf16x8 b2 = *(const bf16x8*)&sB[(colL + 32) * 136 + kb];
        bf16x8 b3 = *(const bf16x8*)&sB[(colL + 48) * 136 + kb];
        acc0 = __builtin_amdgcn_mfma_f32_16x16x32_bf16(a, b0, acc0, 0, 0, 0);
        acc1 = __builtin_amdgcn_mfma_f32_16x16x32_bf16(a, b1, acc1, 0, 0, 0);
        acc2 = __builtin_amdgcn_mfma_f32_16x16x32_bf16(a, b2, acc2, 0, 0, 0);
        acc3 = __builtin_amdgcn_mfma_f32_16x16x32_bf16(a, b3, acc3, 0, 0, 0);
    }
    const float bias0 = b[colL +  0];
    const float bias1 = b[colL + 16];
    const float bias2 = b[colL + 32];
    const float bias3 = b[colL + 48];
    const int rbase = gbase + 16 * w + kq * 4;
#pragma unroll
    for (int j = 0; j < 4; ++j) {
        int grow = rbase + j;
        if (grow < n) {
            size_t o = (size_t)grow * 64;
            outb[o + colL +  0] = (unsigned short)bf16_rne(fmaxf(acc0[j] + bias0, 0.f));
            outb[o + colL + 16] = (unsigned short)bf16_rne(fmaxf(acc1[j] + bias1, 0.f));
            outb[o + colL + 32] = (unsigned short)bf16_rne(fmaxf(acc2[j] + bias2, 0.f));
            outb[o + colL + 48] = (unsigned short)bf16_rne(fmaxf(acc3[j] + bias3, 0.f));
        }
    }
}

// ---------------------------------------------------------------------------
// K2 (MFMA): loc_x = relu([loc_feat || emb[qid]] @ W_loc + b_loc) -> bf16
// K padded 144->160 = 5 exact K-steps of 32; tail zeros in A and B.
// ---------------------------------------------------------------------------
__global__ __launch_bounds__(256) void k_loc(const float* __restrict__ feat,
                                             const int* __restrict__ qid,
                                             const float* __restrict__ emb,
                                             const float* __restrict__ W,
                                             const float* __restrict__ b,
                                             unsigned short* __restrict__ outb, int n) {
    __shared__ unsigned short sA[64 * 168];  // 21.5 KB
    __shared__ unsigned short sB[64 * 168];  // 21.5 KB, Wt[col][k]
    const int t = threadIdx.x;
    const int gbase = blockIdx.x * RBLK;
    for (int idx = t; idx < 72 * 64; idx += 256) {
        int kp = idx >> 6, c = idx & 63;
        float w0 = W[(2 * kp + 0) * 64 + c];
        float w1 = W[(2 * kp + 1) * 64 + c];
        *(unsigned*)&sB[c * 168 + 2 * kp] = bf16_rne(w0) | (bf16_rne(w1) << 16);
    }
    for (int idx = t; idx < 64 * 2; idx += 256) {
        int c = idx >> 1, h = idx & 1;
        *(uint4*)&sB[c * 168 + 144 + h * 8] = make_uint4(0, 0, 0, 0);
    }
    for (int idx = t; idx < RBLK * 32; idx += 256) {
        int row = idx >> 5, c4 = idx & 31;
        int grow = gbase + row;
        float4 v = (grow < n) ? ((const float4*)feat)[(size_t)grow * 32 + c4]
                              : make_float4(0.f, 0.f, 0.f, 0.f);
        uint2 p = make_uint2(bf16_rne(v.x) | (bf16_rne(v.y) << 16),
                             bf16_rne(v.z) | (bf16_rne(v.w) << 16));
        *(uint2*)&sA[row * 168 + c4 * 4] = p;
    }
    for (int idx = t; idx < RBLK * 4; idx += 256) {
        int row = idx >> 2, e4 = idx & 3;
        int grow = gbase + row;
        int q = (grow < n) ? qid[grow] : 0;
        float4 v = ((const float4*)emb)[(size_t)q * 4 + e4];
        uint2 p = make_uint2(bf16_rne(v.x) | (bf16_rne(v.y) << 16),
                             bf16_rne(v.z) | (bf16_rne(v.w) << 16));
        *(uint2*)&sA[row * 168 + 128 + e4 * 4] = p;
    }
    for (int idx = t; idx < RBLK * 2; idx += 256) {
        int row = idx >> 1, h = idx & 1;
        *(uint4*)&sA[row * 168 + 144 + h * 8] = make_uint4(0, 0, 0, 0);
    }
    __syncthreads();
    const int lane = t & 63;
    const int w = t >> 6;
    const int colL = lane & 15;
    const int kq = lane >> 4;
    f32x4 acc0 = {0.f, 0.f, 0.f, 0.f}, acc1 = acc0, acc2 = acc0, acc3 = acc0;
#pragma unroll
    for (int s = 0; s < 5; ++s) {
        const int kb = s * 32 + kq * 8;
        bf16x8 a  = *(const bf16x8*)&sA[(16 * w + colL) * 168 + kb];
        bf16x8 b0 = *(const bf16x8*)&sB[(colL +  0) * 168 + kb];
        bf16x8 b1 = *(const bf16x8*)&sB[(colL + 16) * 168 + kb];
        bf16x8 b2 = *(const bf16x8*)&sB[(colL + 32) * 168 + kb];
        bf16x8 b3 = *(const bf16x8*)&sB[(colL + 48) * 168 + kb];
        acc0 = __builtin_amdgcn_mfma_f32_16x16x32_bf16(a, b0, acc0, 0, 0, 0);
        acc1 = __builtin_amdgcn_mfma_f32_16x16x32_bf16(a, b1, acc1, 0, 0, 0);
        acc2 = __builtin_amdgcn_mfma_f32_16x16x32_bf16(a, b2, acc2, 0, 0, 0);
        acc3 = __builtin_amdgcn_mfma_f32_16x16x32_bf16(a, b3, acc3, 0, 0, 0);
    }
    const float bias0 = b[colL +  0];
    const float bias1 = b[colL + 16];
    const float bias2 = b[colL + 32];
    const float bias3 = b[colL + 48];
    const int rbase = gbase + 16 * w + kq * 4;
#pragma unroll
    for (int j = 0; j < 4; ++j) {
        int grow = rbase + j;
        if (grow < n) {
            size_t o = (size_t)grow * 64;
            outb[o + colL +  0] = (unsigned short)bf16_rne(fmaxf(acc0[j] + bias0, 0.f));
            outb[o + colL + 16] = (unsigned short)bf16_rne(fmaxf(acc1[j] + bias1, 0.f));
            outb[o + colL + 32] = (unsigned short)bf16_rne(fmaxf(acc2[j] + bias2, 0.f));
            outb[o + colL + 48] = (unsigned short)bf16_rne(fmaxf(acc3[j] + bias3, 0.f));
        }
    }
}

// ---------------------------------------------------------------------------
// k_bin: bucket edges by dst>>8; payload packed to 4B: src(24b) | dstlow(8b).
// ---------------------------------------------------------------------------
__global__ __launch_bounds__(256) void k_bin(const int* __restrict__ ei,
                                             int* __restrict__ bucket_cnt,
                                             unsigned* __restrict__ binned, int n) {
    __shared__ int h[NB];
    __shared__ int base[NB];
    const int t = threadIdx.x;
    for (int i = t; i < NB; i += 256) h[i] = 0;
    __syncthreads();
    const int e0 = blockIdx.x * TILE;
    int src[16], dst[16], rnk[16];
#pragma unroll
    for (int j = 0; j < 16; ++j) {
        int e = e0 + j * 256 + t;
        if (e < n) {
            src[j] = ei[e];
            dst[j] = ei[n + e];
            rnk[j] = atomicAdd(&h[dst[j] >> 8], 1);
        }
    }
    __syncthreads();
    for (int i = t; i < NB; i += 256) {
        int c = h[i];
        base[i] = (c > 0) ? atomicAdd(&bucket_cnt[i], c) : 0;
    }
    __syncthreads();
#pragma unroll
    for (int j = 0; j < 16; ++j) {
        int e = e0 + j * 256 + t;
        if (e < n) {
            int bk = dst[j] >> 8;
            int idx = base[bk] + rnk[j];
            if (idx < BCAP)
                binned[(size_t)bk * BCAP + idx] =
                    (unsigned)src[j] | ((unsigned)(dst[j] & 255) << 24);
        }
    }
}

// ---------------------------------------------------------------------------
// k_bfill: one block per bucket. LDS degree hist -> scan of PADDED degrees
// (pad-to-16) -> deg/row_ex at fixed per-bucket csr stride BCAPP, then
// scatter csr with LDS cursors and fill pad slots with the dummy src N_EVT.
// ---------------------------------------------------------------------------
__global__ __launch_bounds__(256) void k_bfill(const int* __restrict__ bucket_cnt,
                                               const unsigned* __restrict__ binned,
                                               int* __restrict__ deg,
                                               int* __restrict__ row_ex,
                                               int* __restrict__ csr) {
    __shared__ int degl[256];
    __shared__ int sc[256];
    __shared__ int cur[256];
    const int b = blockIdx.x;
    const int t = threadIdx.x;
    const int nb = min(bucket_cnt[b], BCAP);
    const unsigned* bin = binned + (size_t)b * BCAP;
    degl[t] = 0;
    __syncthreads();
    for (int i = t; i < nb; i += 256)
        atomicAdd(&degl[bin[i] >> 24], 1);
    __syncthreads();
    const int v = degl[t];
    const int vpad = (v + 15) & ~15;
    sc[t] = vpad;
    __syncthreads();
    for (int off = 1; off < 256; off <<= 1) {
        int x = (t >= off) ? sc[t - off] : 0;
        __syncthreads();
        sc[t] += x;
        __syncthreads();
    }
    const int ex = b * BCAPP + sc[t] - vpad;  // sum(vpad) <= 5120+3840 < BCAPP
    const int loc = b * 256 + t;
    if (loc < N_LOC) { deg[loc] = v; row_ex[loc] = ex; }
    cur[t] = ex;
    __syncthreads();
    for (int i = t; i < nb; i += 256) {
        unsigned u = bin[i];
        int pos = atomicAdd(&cur[u >> 24], 1);
        csr[pos] = (int)(u & 0x00FFFFFFu);
    }
    // pad slots -> dummy zero-row index (disjoint from scattered range)
    for (int j = v; j < vpad; ++j) csr[ex + j] = N_EVT;
}

// ---------------------------------------------------------------------------
// K4: mean[loc] from bf16-packed evt rows -> bf16-packed mean.
// Padded CSR (multiple of 16): tail-free loop, 8 csr loads + 8 gathers in
// flight per iteration. Dummy rows hit the L1-hot zero row.
// ---------------------------------------------------------------------------
__global__ __launch_bounds__(256, 8) void k_aggr(const unsigned* __restrict__ evtb,
                                                 const int* __restrict__ row_ex,
                                                 const int* __restrict__ deg,
                                                 const int* __restrict__ csr,
                                                 unsigned* __restrict__ meanb, int n) {
    const int lane = threadIdx.x & 63;
    int wid = (blockIdx.x * 256 + threadIdx.x) >> 6;
    wid = __builtin_amdgcn_readfirstlane(wid);
    if (wid >= n) return;
    const int beg = row_ex[wid];
    const int cnt = deg[wid];
    const int cntp = (cnt + 15) & ~15;
    const int half = lane >> 5;   // which edge of each pair
    const int c = lane & 31;      // channel-pair index
    float a0 = 0.0f, a1 = 0.0f;
    for (int i = 0; i < cntp; i += 16) {
        const int bb = beg + i + half;
        int s0 = csr[bb +  0];
        int s1 = csr[bb +  2];
        int s2 = csr[bb +  4];
        int s3 = csr[bb +  6];
        int s4 = csr[bb +  8];
        int s5 = csr[bb + 10];
        int s6 = csr[bb + 12];
        int s7 = csr[bb + 14];
        unsigned u0 = evtb[(size_t)s0 * 32 + c];
        unsigned u1 = evtb[(size_t)s1 * 32 + c];
        unsigned u2 = evtb[(size_t)s2 * 32 + c];
        unsigned u3 = evtb[(size_t)s3 * 32 + c];
        unsigned u4 = evtb[(size_t)s4 * 32 + c];
        unsigned u5 = evtb[(size_t)s5 * 32 + c];
        unsigned u6 = evtb[(size_t)s6 * 32 + c];
        unsigned u7 = evtb[(size_t)s7 * 32 + c];
        a0 += ((bf_lo(u0) + bf_lo(u1)) + (bf_lo(u2) + bf_lo(u3))) +
              ((bf_lo(u4) + bf_lo(u5)) + (bf_lo(u6) + bf_lo(u7)));
        a1 += ((bf_hi(u0) + bf_hi(u1)) + (bf_hi(u2) + bf_hi(u3))) +
              ((bf_hi(u4) + bf_hi(u5)) + (bf_hi(u6) + bf_hi(u7)));
    }
    a0 += __shfl_xor(a0, 32);
    a1 += __shfl_xor(a1, 32);
    const float inv = 1.0f / (float)max(cnt, 1);
    if (lane < 32)
        meanb[(size_t)wid * 32 + c] = bf16_rne(a0 * inv) | (bf16_rne(a1 * inv) << 16);
}

// ---------------------------------------------------------------------------
// K5 (MFMA): x2 = relu([mean||locx] @ [W_l;W_r] + b_l);
//            h = relu(x2 @ W_h1 + b_h1); out = h @ W_h2 + b_h2.
// (validated round 12)
// ---------------------------------------------------------------------------
__global__ __launch_bounds__(256) void k_comb(
    const unsigned* __restrict__ meanb, const unsigned* __restrict__ locxb,
    const float* __restrict__ W_l, const float* __restrict__ b_l,
    const float* __restrict__ W_r,
    const float* __restrict__ W_h1, const float* __restrict__ b_h1,
    const float* __restrict__ W_h2, const float* __restrict__ b_h2,
    float* __restrict__ out, int n)
{
    __shared__ unsigned short sA[64 * 136];
    __shared__ unsigned short sBc[64 * 136];
    __shared__ unsigned short sX[64 * 72];
    __shared__ unsigned short sBh[32 * 72];
    const int t = threadIdx.x;
    const int gbase = blockIdx.x * RBLK;
    for (int idx = t; idx < 64 * 64; idx += 256) {
        int kp = idx >> 6, c = idx & 63;
        float w0, w1;
        if (kp < 32) { w0 = W_l[(2 * kp + 0) * 64 + c]; w1 = W_l[(2 * kp + 1) * 64 + c]; }
        else { w0 = W_r[(2 * kp - 64 + 0) * 64 + c]; w1 = W_r[(2 * kp - 64 + 1) * 64 + c]; }
        *(unsigned*)&sBc[c * 136 + 2 * kp] = bf16_rne(w0) | (bf16_rne(w1) << 16);
    }
    for (int idx = t; idx < 32 * 32; idx += 256) {
        int kp = idx >> 5, c = idx & 31;
        float w0 = W_h1[(2 * kp + 0) * 32 + c];
        float w1 = W_h1[(2 * kp + 1) * 32 + c];
        *(unsigned*)&sBh[c * 72 + 2 * kp] = bf16_rne(w0) | (bf16_rne(w1) << 16);
    }
    for (int idx = t; idx < RBLK * 32; idx += 256) {
        int row = idx >> 5, q = idx & 31;
        int grow = gbase + row;
        uint2 p = make_uint2(0, 0);
        if (grow < n) {
            p = (q < 16) ? ((const uint2*)meanb)[(size_t)grow * 16 + q]
                         : ((const uint2*)locxb)[(size_t)grow * 16 + (q - 16)];
        }
        *(uint2*)&sA[row * 136 + q * 4] = p;
    }
    __syncthreads();
    const int lane = t & 63;
    const int w = t >> 6;
    const int colL = lane & 15;
    const int kq = lane >> 4;
    f32x4 acc0 = {0.f, 0.f, 0.f, 0.f}, acc1 = acc0, acc2 = acc0, acc3 = acc0;
#pragma unroll
    for (int s = 0; s < 4; ++s) {
        const int kb = s * 32 + kq * 8;
        bf16x8 a  = *(const bf16x8*)&sA[(16 * w + colL) * 136 + kb];
        bf16x8 b0 = *(const bf16x8*)&sBc[(colL +  0) * 136 + kb];
        bf16x8 b1 = *(const bf16x8*)&sBc[(colL + 16) * 136 + kb];
        bf16x8 b2 = *(const bf16x8*)&sBc[(colL + 32) * 136 + kb];
        bf16x8 b3 = *(const bf16x8*)&sBc[(colL + 48) * 136 + kb];
        acc0 = __builtin_amdgcn_mfma_f32_16x16x32_bf16(a, b0, acc0, 0, 0, 0);
        acc1 = __builtin_amdgcn_mfma_f32_16x16x32_bf16(a, b1, acc1, 0, 0, 0);
        acc2 = __builtin_amdgcn_mfma_f32_16x16x32_bf16(a, b2, acc2, 0, 0, 0);
        acc3 = __builtin_amdgcn_mfma_f32_16x16x32_bf16(a, b3, acc3, 0, 0, 0);
    }
    {
        const float bias0 = b_l[colL +  0];
        const float bias1 = b_l[colL + 16];
        const float bias2 = b_l[colL + 32];
        const float bias3 = b_l[colL + 48];
#pragma unroll
        for (int j = 0; j < 4; ++j) {
            int row = 16 * w + kq * 4 + j;
            sX[row * 72 + colL +  0] = (unsigned short)bf16_rne(fmaxf(acc0[j] + bias0, 0.f));
            sX[row * 72 + colL + 16] = (unsigned short)bf16_rne(fmaxf(acc1[j] + bias1, 0.f));
            sX[row * 72 + colL + 32] = (unsigned short)bf16_rne(fmaxf(acc2[j] + bias2, 0.f));
            sX[row * 72 + colL + 48] = (unsigned short)bf16_rne(fmaxf(acc3[j] + bias3, 0.f));
        }
    }
    // wave w wrote rows 16w..16w+15 and reads only those: no barrier needed.
    f32x4 h0 = {0.f, 0.f, 0.f, 0.f}, h1 = h0;
#pragma unroll
    for (int s = 0; s < 2; ++s) {
        const int kb = s * 32 + kq * 8;
        bf16x8 a  = *(const bf16x8*)&sX[(16 * w + colL) * 72 + kb];
        bf16x8 b0 = *(const bf16x8*)&sBh[(colL +  0) * 72 + kb];
        bf16x8 b1 = *(const bf16x8*)&sBh[(colL + 16) * 72 + kb];
        h0 = __builtin_amdgcn_mfma_f32_16x16x32_bf16(a, b0, h0, 0, 0, 0);
        h1 = __builtin_amdgcn_mfma_f32_16x16x32_bf16(a, b1, h1, 0, 0, 0);
    }
    {
        const float bh1c0 = b_h1[colL];
        const float bh1c1 = b_h1[colL + 16];
        const float wh2c0 = W_h2[colL];
        const float wh2c1 = W_h2[colL + 16];
        const float bh2 = b_h2[0];
#pragma unroll
        for (int j = 0; j < 4; ++j) {
            float p = fmaxf(h0[j] + bh1c0, 0.f) * wh2c0 +
                      fmaxf(h1[j] + bh1c1, 0.f) * wh2c1;
            p += __shfl_xor(p, 1);
            p += __shfl_xor(p, 2);
            p += __shfl_xor(p, 4);
            p += __shfl_xor(p, 8);
            int grow = gbase + 16 * w + kq * 4 + j;
            if (colL == 0 && grow < n) out[grow] = p + bh2;
        }
    }
}

// ---------------------------------------------------------------------------
extern "C" void kernel_launch(void* const* d_in, const int* in_sizes, int n_in,
                              void* d_out, int out_size, void* d_ws, size_t ws_size,
                              hipStream_t stream) {
    const float* loc_feat = (const float*)d_in[0];
    const float* evt_feat = (const float*)d_in[1];
    const int*   qid      = (const int*)d_in[2];
    const int*   ei       = (const int*)d_in[3];
    const float* emb      = (const float*)d_in[4];
    const float* W_loc    = (const float*)d_in[5];
    const float* b_loc    = (const float*)d_in[6];
    const float* W_evt    = (const float*)d_in[7];
    const float* b_evt    = (const float*)d_in[8];
    const float* W_l      = (const float*)d_in[9];
    const float* b_l      = (const float*)d_in[10];
    const float* W_r      = (const float*)d_in[11];
    const float* W_h1     = (const float*)d_in[12];
    const float* b_h1     = (const float*)d_in[13];
    const float* W_h2     = (const float*)d_in[14];
    const float* b_h2     = (const float*)d_in[15];
    float* out = (float*)d_out;

    char* ws = (char*)d_ws;
    size_t off = 0;
    auto alloc = [&](size_t bytes) -> void* {
        void* p = ws + off;
        off += (bytes + 255) & ~(size_t)255;
        return p;
    };
    unsigned* evtb  = (unsigned*)alloc((size_t)(N_EVT + 1) * 32 * 4); // bf16 evt_x + zero row
    unsigned* locxb = (unsigned*)alloc((size_t)N_LOC * 32 * 4);       // bf16 loc_x (12.8 MB)
    unsigned* meanb = (unsigned*)alloc((size_t)N_LOC * 32 * 4);       // bf16 mean (12.8 MB)
    unsigned* binned= (unsigned*)alloc((size_t)NB * BCAP * 4);        // 8 MB packed
    int*   deg      = (int*)alloc((size_t)N_LOC * 4);
    int*   row_ex   = (int*)alloc((size_t)(N_LOC + 1) * 4);
    int*   csr      = (int*)alloc((size_t)NB * BCAPP * 4);            // 14.4 MB padded
    int*   bucket_cnt = (int*)alloc((size_t)NB * 4);
    (void)ws_size; (void)in_sizes; (void)n_in; (void)out_size;

    const int dense_grid = (N_LOC + RBLK - 1) / RBLK;  // 1563
    // k_evt block 0 zeroes bucket_cnt + dummy row (stream order covers k_bin/k_aggr)
    k_evt<<<dense_grid, 256, 0, stream>>>(evt_feat, W_evt, b_evt,
                                          (unsigned short*)evtb, bucket_cnt,
                                          evtb + (size_t)N_EVT * 32, N_EVT);
    k_loc<<<dense_grid, 256, 0, stream>>>(loc_feat, qid, emb, W_loc, b_loc,
                                          (unsigned short*)locxb, N_LOC);
    k_bin<<<(N_EDGE + TILE - 1) / TILE, 256, 0, stream>>>(ei, bucket_cnt, binned, N_EDGE);
    k_bfill<<<NB, 256, 0, stream>>>(bucket_cnt, binned, deg, row_ex, csr);
    k_aggr<<<N_LOC / 4, 256, 0, stream>>>(evtb, row_ex, deg, csr, meanb, N_LOC);
    k_comb<<<dense_grid, 256, 0, stream>>>(meanb, locxb, W_l, b_l, W_r,
                                           W_h1, b_h1, W_h2, b_h2, out, N_LOC);
}

// Round 16
// 124.291 us; speedup vs baseline: 2.5553x; 1.1420x over previous
//
#include <hip/hip_runtime.h>

#define N_LOC 100000
#define N_EVT 100000
#define N_EDGE 1600000
#define NB 391        // buckets of 256 dst values
#define NBIN 391      // bin blocks: ceil(N_EDGE/TILE)
#define SEGCAP 48     // per (block,bucket) segment capacity (mean 10.5)
#define BCAPP 9216    // padded csr capacity per bucket
#define TILE 4096     // edges per bin block (256 thr x 16)
#define RBLK 64       // rows per block in dense kernels (4 waves x 16)
#define DGRID 1563    // ceil(100000/64)

typedef short bf16x8 __attribute__((ext_vector_type(8)));
typedef float f32x4  __attribute__((ext_vector_type(4)));

__device__ __forceinline__ unsigned bf16_rne(float x) {
    unsigned u = __float_as_uint(x);
    return (u + 0x7fffu + ((u >> 16) & 1u)) >> 16;
}
__device__ __forceinline__ float bf_lo(unsigned u) { return __uint_as_float(u << 16); }
__device__ __forceinline__ float bf_hi(unsigned u) { return __uint_as_float(u & 0xffff0000u); }

// ---------------------------------------------------------------------------
// k_front: fused {bin | evt | loc} roles by blockIdx range.
//   bin (blocks 0..390): LDS hist -> unconditional counts matrix + segments
//       (no global atomics, no init dependency). Block 0 zeroes dummy row.
//   evt (next 1563): MFMA evt_x -> bf16 (validated round 11 structure)
//   loc (next 1563): MFMA loc_x -> bf16 (validated round 12 structure)
// ---------------------------------------------------------------------------
__global__ __launch_bounds__(256) void k_front(
    const float* __restrict__ evt_feat, const float* __restrict__ W_evt,
    const float* __restrict__ b_evt, unsigned short* __restrict__ evtb,
    const float* __restrict__ loc_feat, const int* __restrict__ qid,
    const float* __restrict__ emb, const float* __restrict__ W_loc,
    const float* __restrict__ b_loc, unsigned short* __restrict__ locxb,
    const int* __restrict__ ei, int* __restrict__ cntm,
    unsigned* __restrict__ seg, unsigned* __restrict__ dummy_row)
{
    __shared__ __align__(16) unsigned char smem[43008];
    const int bid = blockIdx.x;
    const int t = threadIdx.x;

    if (bid < NBIN) {
        // ---------------- bin role ----------------
        int* h = (int*)smem;  // NB ints
        if (bid == 0 && t < 32) dummy_row[t] = 0u;
        for (int i = t; i < NB; i += 256) h[i] = 0;
        __syncthreads();
        const int e0 = bid * TILE;
        int srcv[16], dstv[16], rnk[16];
#pragma unroll
        for (int j = 0; j < 16; ++j) {
            int e = e0 + j * 256 + t;
            if (e < N_EDGE) {
                srcv[j] = ei[e];
                dstv[j] = ei[N_EDGE + e];
                rnk[j] = atomicAdd(&h[dstv[j] >> 8], 1);
            }
        }
        __syncthreads();
        for (int i = t; i < NB; i += 256)
            cntm[(size_t)bid * NB + i] = min(h[i], SEGCAP);
#pragma unroll
        for (int j = 0; j < 16; ++j) {
            int e = e0 + j * 256 + t;
            if (e < N_EDGE && rnk[j] < SEGCAP)
                seg[((size_t)bid * NB + (dstv[j] >> 8)) * SEGCAP + rnk[j]] =
                    (unsigned)srcv[j] | ((unsigned)(dstv[j] & 255) << 24);
        }
        return;
    }

    const int lane = t & 63;
    const int w = t >> 6;
    const int colL = lane & 15;
    const int kq = lane >> 4;

    int db = bid - NBIN;
    if (db < DGRID) {
        // ---------------- evt role ----------------
        unsigned short* sA = (unsigned short*)smem;          // 64*136
        unsigned short* sB = sA + 64 * 136;                  // 64*136
        const int gbase = db * RBLK;
        for (int idx = t; idx < 4096; idx += 256) {
            int kp = idx >> 6, c = idx & 63;
            float w0 = W_evt[(2 * kp + 0) * 64 + c];
            float w1 = W_evt[(2 * kp + 1) * 64 + c];
            *(unsigned*)&sB[c * 136 + 2 * kp] = bf16_rne(w0) | (bf16_rne(w1) << 16);
        }
        for (int idx = t; idx < RBLK * 32; idx += 256) {
            int row = idx >> 5, c4 = idx & 31;
            int grow = gbase + row;
            float4 v = (grow < N_EVT) ? ((const float4*)evt_feat)[(size_t)grow * 32 + c4]
                                      : make_float4(0.f, 0.f, 0.f, 0.f);
            uint2 p = make_uint2(bf16_rne(v.x) | (bf16_rne(v.y) << 16),
                                 bf16_rne(v.z) | (bf16_rne(v.w) << 16));
            *(uint2*)&sA[row * 136 + c4 * 4] = p;
        }
        __syncthreads();
        f32x4 acc0 = {0.f, 0.f, 0.f, 0.f}, acc1 = acc0, acc2 = acc0, acc3 = acc0;
#pragma unroll
        for (int s = 0; s < 4; ++s) {
            const int kb = s * 32 + kq * 8;
            bf16x8 a  = *(const bf16x8*)&sA[(16 * w + colL) * 136 + kb];
            bf16x8 b0 = *(const bf16x8*)&sB[(colL +  0) * 136 + kb];
            bf16x8 b1 = *(const bf16x8*)&sB[(colL + 16) * 136 + kb];
            bf16x8 b2 = *(const bf16x8*)&sB[(colL + 32) * 136 + kb];
            bf16x8 b3 = *(const bf16x8*)&sB[(colL + 48) * 136 + kb];
            acc0 = __builtin_amdgcn_mfma_f32_16x16x32_bf16(a, b0, acc0, 0, 0, 0);
            acc1 = __builtin_amdgcn_mfma_f32_16x16x32_bf16(a, b1, acc1, 0, 0, 0);
            acc2 = __builtin_amdgcn_mfma_f32_16x16x32_bf16(a, b2, acc2, 0, 0, 0);
            acc3 = __builtin_amdgcn_mfma_f32_16x16x32_bf16(a, b3, acc3, 0, 0, 0);
        }
        const float bias0 = b_evt[colL +  0];
        const float bias1 = b_evt[colL + 16];
        const float bias2 = b_evt[colL + 32];
        const float bias3 = b_evt[colL + 48];
        const int rbase = gbase + 16 * w + kq * 4;
#pragma unroll
        for (int j = 0; j < 4; ++j) {
            int grow = rbase + j;
            if (grow < N_EVT) {
                size_t o = (size_t)grow * 64;
                evtb[o + colL +  0] = (unsigned short)bf16_rne(fmaxf(acc0[j] + bias0, 0.f));
                evtb[o + colL + 16] = (unsigned short)bf16_rne(fmaxf(acc1[j] + bias1, 0.f));
                evtb[o + colL + 32] = (unsigned short)bf16_rne(fmaxf(acc2[j] + bias2, 0.f));
                evtb[o + colL + 48] = (unsigned short)bf16_rne(fmaxf(acc3[j] + bias3, 0.f));
            }
        }
        return;
    }

    // ---------------- loc role ----------------
    {
        db -= DGRID;
        unsigned short* sA = (unsigned short*)smem;          // 64*168
        unsigned short* sB = sA + 64 * 168;                  // 64*168
        const int gbase = db * RBLK;
        for (int idx = t; idx < 72 * 64; idx += 256) {
            int kp = idx >> 6, c = idx & 63;
            float w0 = W_loc[(2 * kp + 0) * 64 + c];
            float w1 = W_loc[(2 * kp + 1) * 64 + c];
            *(unsigned*)&sB[c * 168 + 2 * kp] = bf16_rne(w0) | (bf16_rne(w1) << 16);
        }
        for (int idx = t; idx < 64 * 2; idx += 256) {
            int c = idx >> 1, h2 = idx & 1;
            *(uint4*)&sB[c * 168 + 144 + h2 * 8] = make_uint4(0, 0, 0, 0);
        }
        for (int idx = t; idx < RBLK * 32; idx += 256) {
            int row = idx >> 5, c4 = idx & 31;
            int grow = gbase + row;
            float4 v = (grow < N_LOC) ? ((const float4*)loc_feat)[(size_t)grow * 32 + c4]
                                      : make_float4(0.f, 0.f, 0.f, 0.f);
            uint2 p = make_uint2(bf16_rne(v.x) | (bf16_rne(v.y) << 16),
                                 bf16_rne(v.z) | (bf16_rne(v.w) << 16));
            *(uint2*)&sA[row * 168 + c4 * 4] = p;
        }
        for (int idx = t; idx < RBLK * 4; idx += 256) {
            int row = idx >> 2, e4 = idx & 3;
            int grow = gbase + row;
            int q = (grow < N_LOC) ? qid[grow] : 0;
            float4 v = ((const float4*)emb)[(size_t)q * 4 + e4];
            uint2 p = make_uint2(bf16_rne(v.x) | (bf16_rne(v.y) << 16),
                                 bf16_rne(v.z) | (bf16_rne(v.w) << 16));
            *(uint2*)&sA[row * 168 + 128 + e4 * 4] = p;
        }
        for (int idx = t; idx < RBLK * 2; idx += 256) {
            int row = idx >> 1, h2 = idx & 1;
            *(uint4*)&sA[row * 168 + 144 + h2 * 8] = make_uint4(0, 0, 0, 0);
        }
        __syncthreads();
        f32x4 acc0 = {0.f, 0.f, 0.f, 0.f}, acc1 = acc0, acc2 = acc0, acc3 = acc0;
#pragma unroll
        for (int s = 0; s < 5; ++s) {
            const int kb = s * 32 + kq * 8;
            bf16x8 a  = *(const bf16x8*)&sA[(16 * w + colL) * 168 + kb];
            bf16x8 b0 = *(const bf16x8*)&sB[(colL +  0) * 168 + kb];
            bf16x8 b1 = *(const bf16x8*)&sB[(colL + 16) * 168 + kb];
            bf16x8 b2 = *(const bf16x8*)&sB[(colL + 32) * 168 + kb];
            bf16x8 b3 = *(const bf16x8*)&sB[(colL + 48) * 168 + kb];
            acc0 = __builtin_amdgcn_mfma_f32_16x16x32_bf16(a, b0, acc0, 0, 0, 0);
            acc1 = __builtin_amdgcn_mfma_f32_16x16x32_bf16(a, b1, acc1, 0, 0, 0);
            acc2 = __builtin_amdgcn_mfma_f32_16x16x32_bf16(a, b2, acc2, 0, 0, 0);
            acc3 = __builtin_amdgcn_mfma_f32_16x16x32_bf16(a, b3, acc3, 0, 0, 0);
        }
        const float bias0 = b_loc[colL +  0];
        const float bias1 = b_loc[colL + 16];
        const float bias2 = b_loc[colL + 32];
        const float bias3 = b_loc[colL + 48];
        const int rbase = gbase + 16 * w + kq * 4;
#pragma unroll
        for (int j = 0; j < 4; ++j) {
            int grow = rbase + j;
            if (grow < N_LOC) {
                size_t o = (size_t)grow * 64;
                locxb[o + colL +  0] = (unsigned short)bf16_rne(fmaxf(acc0[j] + bias0, 0.f));
                locxb[o + colL + 16] = (unsigned short)bf16_rne(fmaxf(acc1[j] + bias1, 0.f));
                locxb[o + colL + 32] = (unsigned short)bf16_rne(fmaxf(acc2[j] + bias2, 0.f));
                locxb[o + colL + 48] = (unsigned short)bf16_rne(fmaxf(acc3[j] + bias3, 0.f));
            }
        }
    }
}

// ---------------------------------------------------------------------------
// k_bfill v2: one block per bucket. Reads the 391-count column + segments.
// Pass 1: LDS degree histogram. Pad-to-16 scan -> deg/row_ex (fixed stride
// BCAPP). Pass 2: cursor scatter into csr + dummy pad fill.
// ---------------------------------------------------------------------------
__global__ __launch_bounds__(256) void k_bfill(const int* __restrict__ cntm,
                                               const unsigned* __restrict__ seg,
                                               int* __restrict__ deg,
                                               int* __restrict__ row_ex,
                                               int* __restrict__ csr) {
    __shared__ int cnt0[NBIN];
    __shared__ int degl[256];
    __shared__ int sc[256];
    __shared__ int cur[256];
    const int b = blockIdx.x;
    const int t = threadIdx.x;
    for (int i = t; i < NBIN; i += 256) cnt0[i] = cntm[(size_t)i * NB + b];
    degl[t] = 0;
    __syncthreads();
    // pass 1: degree histogram
    for (int blk = t; blk < NBIN; blk += 256) {
        const int c = cnt0[blk];
        const unsigned* s = seg + ((size_t)blk * NB + b) * SEGCAP;
        for (int j = 0; j < c; ++j) atomicAdd(&degl[s[j] >> 24], 1);
    }
    __syncthreads();
    const int v = degl[t];
    const int vpad = (v + 15) & ~15;
    sc[t] = vpad;
    __syncthreads();
    for (int off = 1; off < 256; off <<= 1) {
        int x = (t >= off) ? sc[t - off] : 0;
        __syncthreads();
        sc[t] += x;
        __syncthreads();
    }
    const int ex = b * BCAPP + sc[t] - vpad;
    const int loc = b * 256 + t;
    if (loc < N_LOC) { deg[loc] = v; row_ex[loc] = ex; }
    cur[t] = ex;
    __syncthreads();
    // pass 2: scatter
    for (int blk = t; blk < NBIN; blk += 256) {
        const int c = cnt0[blk];
        const unsigned* s = seg + ((size_t)blk * NB + b) * SEGCAP;
        for (int j = 0; j < c; ++j) {
            unsigned u = s[j];
            int pos = atomicAdd(&cur[u >> 24], 1);
            csr[pos] = (int)(u & 0x00FFFFFFu);
        }
    }
    for (int j = v; j < vpad; ++j) csr[ex + j] = N_EVT;
}

// ---------------------------------------------------------------------------
// K4: mean[loc] from bf16-packed evt rows -> bf16-packed mean.
// (validated round 14: padded CSR, tail-free 16-deep gather pipeline)
// ---------------------------------------------------------------------------
__global__ __launch_bounds__(256, 8) void k_aggr(const unsigned* __restrict__ evtb,
                                                 const int* __restrict__ row_ex,
                                                 const int* __restrict__ deg,
                                                 const int* __restrict__ csr,
                                                 unsigned* __restrict__ meanb, int n) {
    const int lane = threadIdx.x & 63;
    int wid = (blockIdx.x * 256 + threadIdx.x) >> 6;
    wid = __builtin_amdgcn_readfirstlane(wid);
    if (wid >= n) return;
    const int beg = row_ex[wid];
    const int cnt = deg[wid];
    const int cntp = (cnt + 15) & ~15;
    const int half = lane >> 5;
    const int c = lane & 31;
    float a0 = 0.0f, a1 = 0.0f;
    for (int i = 0; i < cntp; i += 16) {
        const int bb = beg + i + half;
        int s0 = csr[bb +  0];
        int s1 = csr[bb +  2];
        int s2 = csr[bb +  4];
        int s3 = csr[bb +  6];
        int s4 = csr[bb +  8];
        int s5 = csr[bb + 10];
        int s6 = csr[bb + 12];
        int s7 = csr[bb + 14];
        unsigned u0 = evtb[(size_t)s0 * 32 + c];
        unsigned u1 = evtb[(size_t)s1 * 32 + c];
        unsigned u2 = evtb[(size_t)s2 * 32 + c];
        unsigned u3 = evtb[(size_t)s3 * 32 + c];
        unsigned u4 = evtb[(size_t)s4 * 32 + c];
        unsigned u5 = evtb[(size_t)s5 * 32 + c];
        unsigned u6 = evtb[(size_t)s6 * 32 + c];
        unsigned u7 = evtb[(size_t)s7 * 32 + c];
        a0 += ((bf_lo(u0) + bf_lo(u1)) + (bf_lo(u2) + bf_lo(u3))) +
              ((bf_lo(u4) + bf_lo(u5)) + (bf_lo(u6) + bf_lo(u7)));
        a1 += ((bf_hi(u0) + bf_hi(u1)) + (bf_hi(u2) + bf_hi(u3))) +
              ((bf_hi(u4) + bf_hi(u5)) + (bf_hi(u6) + bf_hi(u7)));
    }
    a0 += __shfl_xor(a0, 32);
    a1 += __shfl_xor(a1, 32);
    const float inv = 1.0f / (float)max(cnt, 1);
    if (lane < 32)
        meanb[(size_t)wid * 32 + c] = bf16_rne(a0 * inv) | (bf16_rne(a1 * inv) << 16);
}

// ---------------------------------------------------------------------------
// K5 (MFMA): x2 = relu([mean||locx] @ [W_l;W_r] + b_l);
//            h = relu(x2 @ W_h1 + b_h1); out = h @ W_h2 + b_h2.
// (validated round 12)
// ---------------------------------------------------------------------------
__global__ __launch_bounds__(256) void k_comb(
    const unsigned* __restrict__ meanb, const unsigned* __restrict__ locxb,
    const float* __restrict__ W_l, const float* __restrict__ b_l,
    const float* __restrict__ W_r,
    const float* __restrict__ W_h1, const float* __restrict__ b_h1,
    const float* __restrict__ W_h2, const float* __restrict__ b_h2,
    float* __restrict__ out, int n)
{
    __shared__ unsigned short sA[64 * 136];
    __shared__ unsigned short sBc[64 * 136];
    __shared__ unsigned short sX[64 * 72];
    __shared__ unsigned short sBh[32 * 72];
    const int t = threadIdx.x;
    const int gbase = blockIdx.x * RBLK;
    for (int idx = t; idx < 64 * 64; idx += 256) {
        int kp = idx >> 6, c = idx & 63;
        float w0, w1;
        if (kp < 32) { w0 = W_l[(2 * kp + 0) * 64 + c]; w1 = W_l[(2 * kp + 1) * 64 + c]; }
        else { w0 = W_r[(2 * kp - 64 + 0) * 64 + c]; w1 = W_r[(2 * kp - 64 + 1) * 64 + c]; }
        *(unsigned*)&sBc[c * 136 + 2 * kp] = bf16_rne(w0) | (bf16_rne(w1) << 16);
    }
    for (int idx = t; idx < 32 * 32; idx += 256) {
        int kp = idx >> 5, c = idx & 31;
        float w0 = W_h1[(2 * kp + 0) * 32 + c];
        float w1 = W_h1[(2 * kp + 1) * 32 + c];
        *(unsigned*)&sBh[c * 72 + 2 * kp] = bf16_rne(w0) | (bf16_rne(w1) << 16);
    }
    for (int idx = t; idx < RBLK * 32; idx += 256) {
        int row = idx >> 5, q = idx & 31;
        int grow = gbase + row;
        uint2 p = make_uint2(0, 0);
        if (grow < n) {
            p = (q < 16) ? ((const uint2*)meanb)[(size_t)grow * 16 + q]
                         : ((const uint2*)locxb)[(size_t)grow * 16 + (q - 16)];
        }
        *(uint2*)&sA[row * 136 + q * 4] = p;
    }
    __syncthreads();
    const int lane = t & 63;
    const int w = t >> 6;
    const int colL = lane & 15;
    const int kq = lane >> 4;
    f32x4 acc0 = {0.f, 0.f, 0.f, 0.f}, acc1 = acc0, acc2 = acc0, acc3 = acc0;
#pragma unroll
    for (int s = 0; s < 4; ++s) {
        const int kb = s * 32 + kq * 8;
        bf16x8 a  = *(const bf16x8*)&sA[(16 * w + colL) * 136 + kb];
        bf16x8 b0 = *(const bf16x8*)&sBc[(colL +  0) * 136 + kb];
        bf16x8 b1 = *(const bf16x8*)&sBc[(colL + 16) * 136 + kb];
        bf16x8 b2 = *(const bf16x8*)&sBc[(colL + 32) * 136 + kb];
        bf16x8 b3 = *(const bf16x8*)&sBc[(colL + 48) * 136 + kb];
        acc0 = __builtin_amdgcn_mfma_f32_16x16x32_bf16(a, b0, acc0, 0, 0, 0);
        acc1 = __builtin_amdgcn_mfma_f32_16x16x32_bf16(a, b1, acc1, 0, 0, 0);
        acc2 = __builtin_amdgcn_mfma_f32_16x16x32_bf16(a, b2, acc2, 0, 0, 0);
        acc3 = __builtin_amdgcn_mfma_f32_16x16x32_bf16(a, b3, acc3, 0, 0, 0);
    }
    {
        const float bias0 = b_l[colL +  0];
        const float bias1 = b_l[colL + 16];
        const float bias2 = b_l[colL + 32];
        const float bias3 = b_l[colL + 48];
#pragma unroll
        for (int j = 0; j < 4; ++j) {
            int row = 16 * w + kq * 4 + j;
            sX[row * 72 + colL +  0] = (unsigned short)bf16_rne(fmaxf(acc0[j] + bias0, 0.f));
            sX[row * 72 + colL + 16] = (unsigned short)bf16_rne(fmaxf(acc1[j] + bias1, 0.f));
            sX[row * 72 + colL + 32] = (unsigned short)bf16_rne(fmaxf(acc2[j] + bias2, 0.f));
            sX[row * 72 + colL + 48] = (unsigned short)bf16_rne(fmaxf(acc3[j] + bias3, 0.f));
        }
    }
    // wave w wrote rows 16w..16w+15 and reads only those: no barrier needed.
    f32x4 h0 = {0.f, 0.f, 0.f, 0.f}, h1 = h0;
#pragma unroll
    for (int s = 0; s < 2; ++s) {
        const int kb = s * 32 + kq * 8;
        bf16x8 a  = *(const bf16x8*)&sX[(16 * w + colL) * 72 + kb];
        bf16x8 b0 = *(const bf16x8*)&sBh[(colL +  0) * 72 + kb];
        bf16x8 b1 = *(const bf16x8*)&sBh[(colL + 16) * 72 + kb];
        h0 = __builtin_amdgcn_mfma_f32_16x16x32_bf16(a, b0, h0, 0, 0, 0);
        h1 = __builtin_amdgcn_mfma_f32_16x16x32_bf16(a, b1, h1, 0, 0, 0);
    }
    {
        const float bh1c0 = b_h1[colL];
        const float bh1c1 = b_h1[colL + 16];
        const float wh2c0 = W_h2[colL];
        const float wh2c1 = W_h2[colL + 16];
        const float bh2 = b_h2[0];
#pragma unroll
        for (int j = 0; j < 4; ++j) {
            float p = fmaxf(h0[j] + bh1c0, 0.f) * wh2c0 +
                      fmaxf(h1[j] + bh1c1, 0.f) * wh2c1;
            p += __shfl_xor(p, 1);
            p += __shfl_xor(p, 2);
            p += __shfl_xor(p, 4);
            p += __shfl_xor(p, 8);
            int grow = gbase + 16 * w + kq * 4 + j;
            if (colL == 0 && grow < n) out[grow] = p + bh2;
        }
    }
}

// ---------------------------------------------------------------------------
extern "C" void kernel_launch(void* const* d_in, const int* in_sizes, int n_in,
                              void* d_out, int out_size, void* d_ws, size_t ws_size,
                              hipStream_t stream) {
    const float* loc_feat = (const float*)d_in[0];
    const float* evt_feat = (const float*)d_in[1];
    const int*   qid      = (const int*)d_in[2];
    const int*   ei       = (const int*)d_in[3];
    const float* emb      = (const float*)d_in[4];
    const float* W_loc    = (const float*)d_in[5];
    const float* b_loc    = (const float*)d_in[6];
    const float* W_evt    = (const float*)d_in[7];
    const float* b_evt    = (const float*)d_in[8];
    const float* W_l      = (const float*)d_in[9];
    const float* b_l      = (const float*)d_in[10];
    const float* W_r      = (const float*)d_in[11];
    const float* W_h1     = (const float*)d_in[12];
    const float* b_h1     = (const float*)d_in[13];
    const float* W_h2     = (const float*)d_in[14];
    const float* b_h2     = (const float*)d_in[15];
    float* out = (float*)d_out;

    char* ws = (char*)d_ws;
    size_t off = 0;
    auto alloc = [&](size_t bytes) -> void* {
        void* p = ws + off;
        off += (bytes + 255) & ~(size_t)255;
        return p;
    };
    unsigned* evtb  = (unsigned*)alloc((size_t)(N_EVT + 1) * 32 * 4); // bf16 evt_x + zero row
    unsigned* locxb = (unsigned*)alloc((size_t)N_LOC * 32 * 4);       // 12.8 MB
    unsigned* meanb = (unsigned*)alloc((size_t)N_LOC * 32 * 4);       // 12.8 MB
    unsigned* seg   = (unsigned*)alloc((size_t)NBIN * NB * SEGCAP * 4); // 29.4 MB
    int*   cntm     = (int*)alloc((size_t)NBIN * NB * 4);             // 0.6 MB
    int*   deg      = (int*)alloc((size_t)N_LOC * 4);
    int*   row_ex   = (int*)alloc((size_t)(N_LOC + 1) * 4);
    int*   csr      = (int*)alloc((size_t)NB * BCAPP * 4);            // 14.4 MB
    (void)ws_size; (void)in_sizes; (void)n_in; (void)out_size;

    // L1: fused bin + evt + loc (391 + 1563 + 1563 blocks)
    k_front<<<NBIN + 2 * DGRID, 256, 0, stream>>>(
        evt_feat, W_evt, b_evt, (unsigned short*)evtb,
        loc_feat, qid, emb, W_loc, b_loc, (unsigned short*)locxb,
        ei, cntm, seg, evtb + (size_t)N_EVT * 32);
    k_bfill<<<NB, 256, 0, stream>>>(cntm, seg, deg, row_ex, csr);
    k_aggr<<<N_LOC / 4, 256, 0, stream>>>(evtb, row_ex, deg, csr, meanb, N_LOC);
    k_comb<<<DGRID, 256, 0, stream>>>(meanb, locxb, W_l, b_l, W_r,
                                      W_h1, b_h1, W_h2, b_h2, out, N_LOC);
}